// Round 1
// baseline (772.505 us; speedup 1.0000x reference)
//
#include <hip/hip_runtime.h>
#include <cstdint>
#include <cstddef>

// GCN 3-layer forward, MI355X. Structure:
//   CSR build (count/scan/fill) -> [GEMM*dis -> CSR-aggregate]*3 -> log_softmax
// All fp32 this round (correctness baseline); GEMM = 128x64 tile, 8x4/thread.

// ---------------- CSR build ----------------
__global__ void k_count(const int* __restrict__ dst, int* __restrict__ cnt, int E) {
  int e = blockIdx.x * blockDim.x + threadIdx.x;
  if (e < E) atomicAdd(&cnt[dst[e]], 1);
}

__global__ __launch_bounds__(1024) void k_scan(const int* __restrict__ cnt,
                                               int* __restrict__ rs,
                                               int* __restrict__ cur,
                                               float* __restrict__ dis, int n) {
  __shared__ int wsum[16];
  const int tid = threadIdx.x;
  const int lane = tid & 63, wid = tid >> 6;
  int offset = 0;
  for (int base = 0; base < n; base += 1024) {
    int i = base + tid;
    int v = (i < n) ? cnt[i] : 0;
    int x = v;
#pragma unroll
    for (int off = 1; off < 64; off <<= 1) {
      int y = __shfl_up(x, off, 64);
      if (lane >= off) x += y;
    }
    if (lane == 63) wsum[wid] = x;
    __syncthreads();
    if (wid == 0) {
      int w = (lane < 16) ? wsum[lane] : 0;
#pragma unroll
      for (int off = 1; off < 16; off <<= 1) {
        int y = __shfl_up(w, off, 64);
        if (lane >= off) w += y;
      }
      if (lane < 16) wsum[lane] = w;
    }
    __syncthreads();
    int prev = (wid > 0) ? wsum[wid - 1] : 0;
    int excl = offset + prev + (x - v);
    if (i < n) {
      rs[i]  = excl;
      cur[i] = excl;
      dis[i] = rsqrtf((float)(1 + v));  // deg = self-loop + in-edges
    }
    offset += wsum[15];
    __syncthreads();
  }
  if (tid == 0) rs[n] = offset;
}

__global__ void k_fill(const int* __restrict__ src, const int* __restrict__ dst,
                       int* __restrict__ cur, int* __restrict__ csr, int E) {
  int e = blockIdx.x * blockDim.x + threadIdx.x;
  if (e < E) {
    int p = atomicAdd(&cur[dst[e]], 1);
    csr[p] = src[e];
  }
}

// ---------------- GEMM: C[M,256] = A[M,256] @ W[256,256], epilogue *dis[m] ----------------
// 128x64 tile, 256 threads, 8x4 per thread, BK=16.
__global__ __launch_bounds__(256) void k_gemm256(const float* __restrict__ A,
                                                 const float* __restrict__ W,
                                                 const float* __restrict__ dis,
                                                 float* __restrict__ C, int M) {
  constexpr int BM = 128, BN = 64, BK = 16, TM = 8, TN = 4;
  __shared__ float As[BK][BM];
  __shared__ float Ws[BK][BN];
  const int tid = threadIdx.x;
  const int tx = tid & 15, ty = tid >> 4;
  const int m0 = blockIdx.x * BM, n0 = blockIdx.y * BN;
  float acc[TM][TN] = {};

  for (int k0 = 0; k0 < 256; k0 += BK) {
    // A tile: 128x16 floats; each thread 2x float4, stored transposed into As[k][m]
    {
      const int r = tid >> 2;            // 0..63
      const int c = (tid & 3) << 2;      // 0,4,8,12
#pragma unroll
      for (int h = 0; h < 2; ++h) {
        const int row = r + h * 64;
        const int gm = m0 + row;
        float4 av = (gm < M) ? *(const float4*)(A + (size_t)gm * 256 + k0 + c)
                             : make_float4(0.f, 0.f, 0.f, 0.f);
        As[c + 0][row] = av.x; As[c + 1][row] = av.y;
        As[c + 2][row] = av.z; As[c + 3][row] = av.w;
      }
      const int wr = tid >> 4;           // 0..15
      const int wc = (tid & 15) << 2;    // 0..60
      *(float4*)&Ws[wr][wc] = *(const float4*)(W + (size_t)(k0 + wr) * 256 + n0 + wc);
    }
    __syncthreads();
#pragma unroll
    for (int kk = 0; kk < BK; ++kk) {
      float a[TM], b[TN];
      *(float4*)&a[0] = *(const float4*)&As[kk][ty * TM];
      *(float4*)&a[4] = *(const float4*)&As[kk][ty * TM + 4];
      *(float4*)&b[0] = *(const float4*)&Ws[kk][tx * TN];
#pragma unroll
      for (int i = 0; i < TM; ++i)
#pragma unroll
        for (int j = 0; j < TN; ++j) acc[i][j] += a[i] * b[j];
    }
    __syncthreads();
  }
#pragma unroll
  for (int i = 0; i < TM; ++i) {
    const int m = m0 + ty * TM + i;
    if (m < M) {
      const float dd = dis[m];
      float4 o = make_float4(acc[i][0] * dd, acc[i][1] * dd, acc[i][2] * dd, acc[i][3] * dd);
      *(float4*)(C + (size_t)m * 256 + n0 + tx * TN) = o;
    }
  }
}

// ---------------- Aggregate 256-dim: out[d] = relu(dis[d]*(u[d]+sum u[src]) + b) ----------------
// one wave per node, float4 per lane (64*16B = 1KB row)
__global__ __launch_bounds__(256) void k_agg256(const float* __restrict__ u,
                                                const int* __restrict__ rs,
                                                const int* __restrict__ csr,
                                                const float* __restrict__ dis,
                                                const float* __restrict__ b,
                                                float* __restrict__ out, int n) {
  const int wid = threadIdx.x >> 6, lane = threadIdx.x & 63;
  const int d = blockIdx.x * 4 + wid;
  if (d >= n) return;
  const int col = lane << 2;
  float4 acc = *(const float4*)(u + (size_t)d * 256 + col);  // self loop term
  const int p1 = rs[d + 1];
  for (int p = rs[d]; p < p1; ++p) {
    const int s = csr[p];
    const float4 v = *(const float4*)(u + (size_t)s * 256 + col);
    acc.x += v.x; acc.y += v.y; acc.z += v.z; acc.w += v.w;
  }
  const float dd = dis[d];
  const float4 bb = *(const float4*)(b + col);
  float4 o;
  o.x = fmaxf(dd * acc.x + bb.x, 0.f);
  o.y = fmaxf(dd * acc.y + bb.y, 0.f);
  o.z = fmaxf(dd * acc.z + bb.z, 0.f);
  o.w = fmaxf(dd * acc.w + bb.w, 0.f);
  *(float4*)(out + (size_t)d * 256 + col) = o;
}

// ---------------- GEMM: C[M,40] = A[M,256] @ W[256,40], epilogue *dis[m] ----------------
// 640 threads: 64 rows x 10 col-groups (4 cols each); W2 staged in LDS (40KB)
__global__ __launch_bounds__(640) void k_gemm40(const float* __restrict__ A,
                                                const float* __restrict__ W,
                                                const float* __restrict__ dis,
                                                float* __restrict__ C, int M) {
  __shared__ float Ws[256 * 40];
  for (int i = threadIdx.x; i < 256 * 40 / 4; i += 640)
    ((float4*)Ws)[i] = ((const float4*)W)[i];
  __syncthreads();
  const int ng = threadIdx.x % 10;   // col group: cols ng*4..ng*4+3
  const int ml = threadIdx.x / 10;   // 0..63
  const int m = blockIdx.x * 64 + ml;
  if (m >= M) return;
  const float* __restrict__ arow = A + (size_t)m * 256;
  float4 acc = make_float4(0.f, 0.f, 0.f, 0.f);
  const int nc = ng << 2;
#pragma unroll 4
  for (int k = 0; k < 256; k += 4) {
    const float4 a  = *(const float4*)(arow + k);
    const float4 w0 = *(const float4*)&Ws[(k + 0) * 40 + nc];
    const float4 w1 = *(const float4*)&Ws[(k + 1) * 40 + nc];
    const float4 w2 = *(const float4*)&Ws[(k + 2) * 40 + nc];
    const float4 w3 = *(const float4*)&Ws[(k + 3) * 40 + nc];
    acc.x += a.x * w0.x + a.y * w1.x + a.z * w2.x + a.w * w3.x;
    acc.y += a.x * w0.y + a.y * w1.y + a.z * w2.y + a.w * w3.y;
    acc.z += a.x * w0.z + a.y * w1.z + a.z * w2.z + a.w * w3.z;
    acc.w += a.x * w0.w + a.y * w1.w + a.z * w2.w + a.w * w3.w;
  }
  const float dd = dis[m];
  *(float4*)(C + (size_t)m * 40 + nc) =
      make_float4(acc.x * dd, acc.y * dd, acc.z * dd, acc.w * dd);
}

// ---------------- Aggregate 40-dim + bias + log_softmax ----------------
// one wave per node; lanes 0..39 hold the class dims
__global__ __launch_bounds__(256) void k_agg40(const float* __restrict__ u,
                                               const int* __restrict__ rs,
                                               const int* __restrict__ csr,
                                               const float* __restrict__ dis,
                                               const float* __restrict__ b,
                                               float* __restrict__ out, int n) {
  const int wid = threadIdx.x >> 6, lane = threadIdx.x & 63;
  const int d = blockIdx.x * 4 + wid;
  if (d >= n) return;
  const bool act = lane < 40;
  float acc = act ? u[(size_t)d * 40 + lane] : 0.f;
  const int p1 = rs[d + 1];
  for (int p = rs[d]; p < p1; ++p) {
    const int s = csr[p];
    if (act) acc += u[(size_t)s * 40 + lane];
  }
  const float logit = act ? dis[d] * acc + b[lane] : -INFINITY;
  float mx = logit;
#pragma unroll
  for (int off = 32; off; off >>= 1) mx = fmaxf(mx, __shfl_xor(mx, off, 64));
  float ex = act ? expf(logit - mx) : 0.f;
  float sm = ex;
#pragma unroll
  for (int off = 32; off; off >>= 1) sm += __shfl_xor(sm, off, 64);
  if (act) out[(size_t)d * 40 + lane] = logit - mx - logf(sm);
}

// ---------------- launch ----------------
extern "C" void kernel_launch(void* const* d_in, const int* in_sizes, int n_in,
                              void* d_out, int out_size, void* d_ws, size_t ws_size,
                              hipStream_t stream) {
  const float* x   = (const float*)d_in[0];
  const int*   ei  = (const int*)d_in[1];
  const float* W0  = (const float*)d_in[2];
  const float* b0  = (const float*)d_in[3];
  const float* W1  = (const float*)d_in[4];
  const float* b1  = (const float*)d_in[5];
  const float* W2  = (const float*)d_in[6];
  const float* b2  = (const float*)d_in[7];
  float* out = (float*)d_out;

  const int N = in_sizes[0] / 256;
  const int E = in_sizes[1] / 2;
  const int* src = ei;
  const int* dst = ei + E;

  // workspace carve (256B aligned)
  char* p = (char*)d_ws;
  auto carve = [&](size_t bytes) {
    char* q = p;
    p += (bytes + 255) & ~(size_t)255;
    return q;
  };
  float* bufA  = (float*)carve((size_t)N * 256 * 4);
  float* bufB  = (float*)carve((size_t)N * 256 * 4);
  float* buf40 = (float*)carve((size_t)N * 40 * 4);
  float* dis   = (float*)carve((size_t)N * 4);
  int*   cnt   = (int*)carve((size_t)N * 4);
  int*   rs    = (int*)carve((size_t)(N + 1) * 4);
  int*   cur   = (int*)carve((size_t)N * 4);
  int*   csr   = (int*)carve((size_t)E * 4);

  // CSR + deg
  hipMemsetAsync(cnt, 0, (size_t)N * 4, stream);
  const int eb = (E + 255) / 256;
  k_count<<<eb, 256, 0, stream>>>(dst, cnt, E);
  k_scan<<<1, 1024, 0, stream>>>(cnt, rs, cur, dis, N);
  k_fill<<<eb, 256, 0, stream>>>(src, dst, cur, csr, E);

  const dim3 ggrid((N + 127) / 128, 4);
  const int agrid = (N + 3) / 4;

  // layer 0
  k_gemm256<<<ggrid, 256, 0, stream>>>(x, W0, dis, bufA, N);
  k_agg256<<<agrid, 256, 0, stream>>>(bufA, rs, csr, dis, b0, bufB, N);
  // layer 1
  k_gemm256<<<ggrid, 256, 0, stream>>>(bufB, W1, dis, bufA, N);
  k_agg256<<<agrid, 256, 0, stream>>>(bufA, rs, csr, dis, b1, bufB, N);
  // layer 2
  k_gemm40<<<(N + 63) / 64, 640, 0, stream>>>(bufB, W2, dis, buf40, N);
  k_agg40<<<agrid, 256, 0, stream>>>(buf40, rs, csr, dis, b2, out, N);
}

// Round 2
// 685.582 us; speedup vs baseline: 1.1268x; 1.1268x over previous
//
#include <hip/hip_runtime.h>
#include <hip/hip_bf16.h>
#include <cstdint>
#include <cstddef>

// GCN 3-layer forward, MI355X (gfx950).
// Round 2: bf16 MFMA GEMMs (16x16x32), bf16 inter-layer feature maps to halve
// aggregation gather traffic. fp32 accumulation everywhere.

typedef unsigned short u16;
typedef unsigned int u32;
typedef __attribute__((ext_vector_type(8))) short bf16x8;
typedef __attribute__((ext_vector_type(4))) float f32x4;

__device__ inline float bfl(u32 u) { return __uint_as_float(u << 16); }
__device__ inline float bfh(u32 u) { return __uint_as_float(u & 0xffff0000u); }
__device__ inline u16 f2bf(float f) {
  __hip_bfloat16 h = __float2bfloat16(f);
  return __builtin_bit_cast(u16, h);
}

// ---------------- CSR build ----------------
__global__ void k_count(const int* __restrict__ dst, int* __restrict__ cnt, int E) {
  int e = blockIdx.x * blockDim.x + threadIdx.x;
  if (e < E) atomicAdd(&cnt[dst[e]], 1);
}

// chunk-per-thread single-block scan (2 serial passes, 1 block-scan)
__global__ __launch_bounds__(1024) void k_scan(const int* __restrict__ cnt,
                                               int* __restrict__ rs,
                                               int* __restrict__ cur,
                                               float* __restrict__ dis, int n) {
  __shared__ int wsum[16];
  const int tid = threadIdx.x;
  const int lane = tid & 63, wid = tid >> 6;
  const int chunk = (n + 1023) >> 10;
  const int lo = min(tid * chunk, n);
  const int hi = min(lo + chunk, n);
  int s = 0;
  for (int i = lo; i < hi; ++i) s += cnt[i];
  int x = s;
#pragma unroll
  for (int off = 1; off < 64; off <<= 1) {
    int y = __shfl_up(x, off, 64);
    if (lane >= off) x += y;
  }
  if (lane == 63) wsum[wid] = x;
  __syncthreads();
  if (wid == 0) {
    int w = (lane < 16) ? wsum[lane] : 0;
#pragma unroll
    for (int off = 1; off < 16; off <<= 1) {
      int y = __shfl_up(w, off, 64);
      if (lane >= off) w += y;
    }
    if (lane < 16) wsum[lane] = w;
  }
  __syncthreads();
  int run = (wid > 0 ? wsum[wid - 1] : 0) + (x - s);  // exclusive prefix
  for (int i = lo; i < hi; ++i) {
    int v = cnt[i];
    rs[i] = run; cur[i] = run;
    dis[i] = rsqrtf((float)(1 + v));
    run += v;
  }
  if (hi == n) rs[n] = run;
}

__global__ void k_fill(const int* __restrict__ src, const int* __restrict__ dst,
                       int* __restrict__ cur, int* __restrict__ csr, int E) {
  int e = blockIdx.x * blockDim.x + threadIdx.x;
  if (e < E) {
    int p = atomicAdd(&cur[dst[e]], 1);
    csr[p] = src[e];
  }
}

// ---------------- converts ----------------
__global__ void k_cvt(const float* __restrict__ x, u16* __restrict__ xb, int total4) {
  int i = blockIdx.x * blockDim.x + threadIdx.x;
  if (i < total4) {
    float4 v = ((const float4*)x)[i];
    ushort4 o;
    o.x = f2bf(v.x); o.y = f2bf(v.y); o.z = f2bf(v.z); o.w = f2bf(v.w);
    ((ushort4*)xb)[i] = o;
  }
}

// Wt[n][k] = bf16(W[k][n]), 256x256
__global__ void k_prepw(const float* __restrict__ W, u16* __restrict__ Wt) {
  int t = blockIdx.x * 256 + threadIdx.x;
  int k = t >> 8, n = t & 255;
  Wt[n * 256 + k] = f2bf(W[t]);
}

// ---------------- MFMA GEMM: C[M,256] = A[M,256] @ W, epilogue *dis[m], bf16 out ----------
// 128x128 block tile, 4 waves (2x2), each wave 64x64 (4x4 of 16x16x32 MFMA), BK=32.
__global__ __launch_bounds__(256) void k_gemm256(const u16* __restrict__ Ab,
                                                 const u16* __restrict__ Wt,
                                                 const float* __restrict__ dis,
                                                 u16* __restrict__ C, int M) {
  __shared__ u16 As[128][40];  // stride 40 bf16 = 80B: 16B-aligned, 2-way banks (free)
  __shared__ u16 Bs[128][40];
  const int tid = threadIdx.x;
  const int wid = tid >> 6, lane = tid & 63;
  const int wave_m = wid >> 1, wave_n = wid & 1;
  const int m0 = blockIdx.x * 128, n0 = blockIdx.y * 128;
  const int quad = lane >> 4, col = lane & 15;

  f32x4 acc[4][4];
#pragma unroll
  for (int i = 0; i < 4; ++i)
#pragma unroll
    for (int j = 0; j < 4; ++j) acc[i][j] = (f32x4){0.f, 0.f, 0.f, 0.f};

  for (int k0 = 0; k0 < 256; k0 += 32) {
    // stage A[128][32] and B[128][32] (B = Wt rows n0..n0+127): 4 x uint4 per thread
#pragma unroll
    for (int h = 0; h < 2; ++h) {
      const int c = tid + h * 256;           // 0..511
      const int r = c >> 2;                  // 0..127
      const int seg = (c & 3) << 3;          // 0,8,16,24
      const int gm = m0 + r;
      uint4 av = make_uint4(0u, 0u, 0u, 0u);
      if (gm < M) av = *(const uint4*)(Ab + (size_t)gm * 256 + k0 + seg);
      *(uint4*)&As[r][seg] = av;
      uint4 bv = *(const uint4*)(Wt + (size_t)(n0 + r) * 256 + k0 + seg);
      *(uint4*)&Bs[r][seg] = bv;
    }
    __syncthreads();

    bf16x8 af[4], bf[4];
#pragma unroll
    for (int i = 0; i < 4; ++i)
      af[i] = *(const bf16x8*)&As[wave_m * 64 + i * 16 + col][quad * 8];
#pragma unroll
    for (int j = 0; j < 4; ++j)
      bf[j] = *(const bf16x8*)&Bs[wave_n * 64 + j * 16 + col][quad * 8];
#pragma unroll
    for (int i = 0; i < 4; ++i)
#pragma unroll
      for (int j = 0; j < 4; ++j)
        acc[i][j] = __builtin_amdgcn_mfma_f32_16x16x32_bf16(af[i], bf[j], acc[i][j], 0, 0, 0);
    __syncthreads();
  }

  // epilogue: C/D layout col=lane&15, row=quad*4+t
#pragma unroll
  for (int i = 0; i < 4; ++i) {
    float dd[4];
    int mbase = m0 + wave_m * 64 + i * 16 + quad * 4;
#pragma unroll
    for (int t = 0; t < 4; ++t) dd[t] = (mbase + t < M) ? dis[mbase + t] : 0.f;
#pragma unroll
    for (int j = 0; j < 4; ++j) {
      const int n = n0 + wave_n * 64 + j * 16 + col;
#pragma unroll
      for (int t = 0; t < 4; ++t) {
        const int m = mbase + t;
        if (m < M) C[(size_t)m * 256 + n] = f2bf(acc[i][j][t] * dd[t]);
      }
    }
  }
}

// ---------------- Aggregate 256-dim bf16: out = relu(dis[d]*(u[d]+sum)+b) -> bf16 ------
__global__ __launch_bounds__(256) void k_agg256(const u16* __restrict__ u,
                                                const int* __restrict__ rs,
                                                const int* __restrict__ csr,
                                                const float* __restrict__ dis,
                                                const float* __restrict__ b,
                                                u16* __restrict__ out, int n) {
  const int wid = threadIdx.x >> 6, lane = threadIdx.x & 63;
  const int d = blockIdx.x * 4 + wid;
  if (d >= n) return;
  const int col = lane << 2;  // 4 bf16 per lane
  uint2 sv = *(const uint2*)(u + (size_t)d * 256 + col);
  float a0 = bfl(sv.x), a1 = bfh(sv.x), a2 = bfl(sv.y), a3 = bfh(sv.y);
  const int p1 = rs[d + 1];
  for (int p = rs[d]; p < p1; ++p) {
    const int s = csr[p];
    const uint2 v = *(const uint2*)(u + (size_t)s * 256 + col);
    a0 += bfl(v.x); a1 += bfh(v.x); a2 += bfl(v.y); a3 += bfh(v.y);
  }
  const float dd = dis[d];
  const float4 bb = *(const float4*)(b + col);
  ushort4 o;
  o.x = f2bf(fmaxf(dd * a0 + bb.x, 0.f));
  o.y = f2bf(fmaxf(dd * a1 + bb.y, 0.f));
  o.z = f2bf(fmaxf(dd * a2 + bb.z, 0.f));
  o.w = f2bf(fmaxf(dd * a3 + bb.w, 0.f));
  *(ushort4*)(out + (size_t)d * 256 + col) = o;
}

// ---------------- GEMM: C[M,40] = A_bf16[M,256] @ W2_f32[256,40], *dis[m] ----------------
__global__ __launch_bounds__(640) void k_gemm40(const u16* __restrict__ A,
                                                const float* __restrict__ W,
                                                const float* __restrict__ dis,
                                                float* __restrict__ C, int M) {
  __shared__ float Ws[256 * 40];
  for (int i = threadIdx.x; i < 256 * 40 / 4; i += 640)
    ((float4*)Ws)[i] = ((const float4*)W)[i];
  __syncthreads();
  const int ng = threadIdx.x % 10;
  const int ml = threadIdx.x / 10;
  const int m = blockIdx.x * 64 + ml;
  if (m >= M) return;
  const u16* __restrict__ arow = A + (size_t)m * 256;
  float4 acc = make_float4(0.f, 0.f, 0.f, 0.f);
  const int nc = ng << 2;
#pragma unroll 2
  for (int k = 0; k < 256; k += 8) {
    const uint4 av = *(const uint4*)(arow + k);
    float a[8] = {bfl(av.x), bfh(av.x), bfl(av.y), bfh(av.y),
                  bfl(av.z), bfh(av.z), bfl(av.w), bfh(av.w)};
#pragma unroll
    for (int kk = 0; kk < 8; ++kk) {
      const float4 w = *(const float4*)&Ws[(k + kk) * 40 + nc];
      acc.x += a[kk] * w.x; acc.y += a[kk] * w.y;
      acc.z += a[kk] * w.z; acc.w += a[kk] * w.w;
    }
  }
  const float dd = dis[m];
  *(float4*)(C + (size_t)m * 40 + nc) =
      make_float4(acc.x * dd, acc.y * dd, acc.z * dd, acc.w * dd);
}

// ---------------- Aggregate 40-dim + bias + log_softmax ----------------
__global__ __launch_bounds__(256) void k_agg40(const float* __restrict__ u,
                                               const int* __restrict__ rs,
                                               const int* __restrict__ csr,
                                               const float* __restrict__ dis,
                                               const float* __restrict__ b,
                                               float* __restrict__ out, int n) {
  const int wid = threadIdx.x >> 6, lane = threadIdx.x & 63;
  const int d = blockIdx.x * 4 + wid;
  if (d >= n) return;
  const bool act = lane < 40;
  float acc = act ? u[(size_t)d * 40 + lane] : 0.f;
  const int p1 = rs[d + 1];
  for (int p = rs[d]; p < p1; ++p) {
    const int s = csr[p];
    if (act) acc += u[(size_t)s * 40 + lane];
  }
  const float logit = act ? dis[d] * acc + b[lane] : -INFINITY;
  float mx = logit;
#pragma unroll
  for (int off = 32; off; off >>= 1) mx = fmaxf(mx, __shfl_xor(mx, off, 64));
  float ex = act ? expf(logit - mx) : 0.f;
  float sm = ex;
#pragma unroll
  for (int off = 32; off; off >>= 1) sm += __shfl_xor(sm, off, 64);
  if (act) out[(size_t)d * 40 + lane] = logit - mx - logf(sm);
}

// ---------------- launch ----------------
extern "C" void kernel_launch(void* const* d_in, const int* in_sizes, int n_in,
                              void* d_out, int out_size, void* d_ws, size_t ws_size,
                              hipStream_t stream) {
  const float* x  = (const float*)d_in[0];
  const int*   ei = (const int*)d_in[1];
  const float* W0 = (const float*)d_in[2];
  const float* b0 = (const float*)d_in[3];
  const float* W1 = (const float*)d_in[4];
  const float* b1 = (const float*)d_in[5];
  const float* W2 = (const float*)d_in[6];
  const float* b2 = (const float*)d_in[7];
  float* out = (float*)d_out;

  const int N = in_sizes[0] / 256;
  const int E = in_sizes[1] / 2;
  const int* src = ei;
  const int* dst = ei + E;

  char* p = (char*)d_ws;
  auto carve = [&](size_t bytes) {
    char* q = p;
    p += (bytes + 255) & ~(size_t)255;
    return q;
  };
  u16*   xb   = (u16*)carve((size_t)N * 256 * 2);
  u16*   bufU = (u16*)carve((size_t)N * 256 * 2);
  u16*   bufH = (u16*)carve((size_t)N * 256 * 2);
  float* u40  = (float*)carve((size_t)N * 40 * 4);
  u16*   Wt0  = (u16*)carve(256 * 256 * 2);
  u16*   Wt1  = (u16*)carve(256 * 256 * 2);
  float* dis  = (float*)carve((size_t)N * 4);
  int*   cnt  = (int*)carve((size_t)N * 4);
  int*   rs   = (int*)carve((size_t)(N + 1) * 4);
  int*   cur  = (int*)carve((size_t)N * 4);
  int*   csr  = (int*)carve((size_t)E * 4);

  // CSR + deg
  hipMemsetAsync(cnt, 0, (size_t)N * 4, stream);
  const int eb = (E + 255) / 256;
  k_count<<<eb, 256, 0, stream>>>(dst, cnt, E);
  k_scan<<<1, 1024, 0, stream>>>(cnt, rs, cur, dis, N);
  k_fill<<<eb, 256, 0, stream>>>(src, dst, cur, csr, E);

  // converts
  k_cvt<<<(N * 64 + 255) / 256, 256, 0, stream>>>(x, xb, N * 64);
  k_prepw<<<256, 256, 0, stream>>>(W0, Wt0);
  k_prepw<<<256, 256, 0, stream>>>(W1, Wt1);

  const dim3 ggrid((N + 127) / 128, 2);
  const int agrid = (N + 3) / 4;

  // layer 0
  k_gemm256<<<ggrid, 256, 0, stream>>>(xb, Wt0, dis, bufU, N);
  k_agg256<<<agrid, 256, 0, stream>>>(bufU, rs, csr, dis, b0, bufH, N);
  // layer 1
  k_gemm256<<<ggrid, 256, 0, stream>>>(bufH, Wt1, dis, bufU, N);
  k_agg256<<<agrid, 256, 0, stream>>>(bufU, rs, csr, dis, b1, bufH, N);
  // layer 2
  k_gemm40<<<(N + 63) / 64, 640, 0, stream>>>(bufH, W2, dis, u40, N);
  k_agg40<<<agrid, 256, 0, stream>>>(u40, rs, csr, dis, b2, out, N);
}

// Round 3
// 561.823 us; speedup vs baseline: 1.3750x; 1.2203x over previous
//
#include <hip/hip_runtime.h>
#include <hip/hip_bf16.h>
#include <cstdint>
#include <cstddef>

// GCN 3-layer forward, MI355X (gfx950).
// Round 3: hierarchical 3-kernel prefix scan (round-2's single-block
// chunk-per-thread scan was a 133us latency trap). GEMM/agg unchanged.

typedef unsigned short u16;
typedef unsigned int u32;
typedef __attribute__((ext_vector_type(8))) short bf16x8;
typedef __attribute__((ext_vector_type(4))) float f32x4;

__device__ inline float bfl(u32 u) { return __uint_as_float(u << 16); }
__device__ inline float bfh(u32 u) { return __uint_as_float(u & 0xffff0000u); }
__device__ inline u16 f2bf(float f) {
  __hip_bfloat16 h = __float2bfloat16(f);
  return __builtin_bit_cast(u16, h);
}

// ---------------- CSR build ----------------
__global__ void k_count(const int* __restrict__ dst, int* __restrict__ cnt, int E) {
  int e = blockIdx.x * blockDim.x + threadIdx.x;
  if (e < E) atomicAdd(&cnt[dst[e]], 1);
}

// phase 1: per-block exclusive scan (1024 elems/block) + block total + dis
__global__ __launch_bounds__(1024) void k_scan1(const int* __restrict__ cnt,
                                                int* __restrict__ rs,
                                                float* __restrict__ dis,
                                                int* __restrict__ bsum, int n) {
  __shared__ int wsum[16];
  const int tid = threadIdx.x;
  const int lane = tid & 63, wid = tid >> 6;
  const int i = blockIdx.x * 1024 + tid;
  const int v = (i < n) ? cnt[i] : 0;
  int x = v;
#pragma unroll
  for (int off = 1; off < 64; off <<= 1) {
    int y = __shfl_up(x, off, 64);
    if (lane >= off) x += y;
  }
  if (lane == 63) wsum[wid] = x;
  __syncthreads();
  if (wid == 0) {
    int w = (lane < 16) ? wsum[lane] : 0;
#pragma unroll
    for (int off = 1; off < 16; off <<= 1) {
      int y = __shfl_up(w, off, 64);
      if (lane >= off) w += y;
    }
    if (lane < 16) wsum[lane] = w;
  }
  __syncthreads();
  const int excl = (wid > 0 ? wsum[wid - 1] : 0) + (x - v);
  if (i < n) {
    rs[i] = excl;
    dis[i] = rsqrtf((float)(1 + v));
  }
  if (tid == 0) bsum[blockIdx.x] = wsum[15];
}

// phase 2: scan the (<=64 here; generic loop) block sums, write grand total to rs[n]
__global__ __launch_bounds__(64) void k_scan2(int* __restrict__ bsum,
                                              int* __restrict__ rs, int nb, int n) {
  const int lane = threadIdx.x;
  int carry = 0;
  for (int base = 0; base < nb; base += 64) {
    const int j = base + lane;
    const int v = (j < nb) ? bsum[j] : 0;
    int x = v;
#pragma unroll
    for (int off = 1; off < 64; off <<= 1) {
      int y = __shfl_up(x, off, 64);
      if (lane >= off) x += y;
    }
    if (j < nb) bsum[j] = carry + (x - v);  // exclusive
    carry += __shfl(x, 63, 64);
  }
  if (lane == 0) rs[n] = carry;
}

// phase 3: add block offsets, write cur
__global__ __launch_bounds__(1024) void k_scan3(int* __restrict__ rs,
                                                int* __restrict__ cur,
                                                const int* __restrict__ bsum, int n) {
  const int i = blockIdx.x * 1024 + threadIdx.x;
  if (i < n) {
    const int r = rs[i] + bsum[blockIdx.x];
    rs[i] = r;
    cur[i] = r;
  }
}

__global__ void k_fill(const int* __restrict__ src, const int* __restrict__ dst,
                       int* __restrict__ cur, int* __restrict__ csr, int E) {
  int e = blockIdx.x * blockDim.x + threadIdx.x;
  if (e < E) {
    int p = atomicAdd(&cur[dst[e]], 1);
    csr[p] = src[e];
  }
}

// ---------------- converts ----------------
__global__ void k_cvt(const float* __restrict__ x, u16* __restrict__ xb, int total4) {
  int i = blockIdx.x * blockDim.x + threadIdx.x;
  if (i < total4) {
    float4 v = ((const float4*)x)[i];
    ushort4 o;
    o.x = f2bf(v.x); o.y = f2bf(v.y); o.z = f2bf(v.z); o.w = f2bf(v.w);
    ((ushort4*)xb)[i] = o;
  }
}

// Wt[n][k] = bf16(W[k][n]), 256x256
__global__ void k_prepw(const float* __restrict__ W, u16* __restrict__ Wt) {
  int t = blockIdx.x * 256 + threadIdx.x;
  int k = t >> 8, n = t & 255;
  Wt[n * 256 + k] = f2bf(W[t]);
}

// ---------------- MFMA GEMM: C[M,256] = A[M,256] @ W, epilogue *dis[m], bf16 out ----------
// 128x128 block tile, 4 waves (2x2), each wave 64x64 (4x4 of 16x16x32 MFMA), BK=32.
__global__ __launch_bounds__(256) void k_gemm256(const u16* __restrict__ Ab,
                                                 const u16* __restrict__ Wt,
                                                 const float* __restrict__ dis,
                                                 u16* __restrict__ C, int M) {
  __shared__ u16 As[128][40];  // stride 40 bf16 = 80B: 16B-aligned, 2-way banks (free)
  __shared__ u16 Bs[128][40];
  const int tid = threadIdx.x;
  const int wid = tid >> 6, lane = tid & 63;
  const int wave_m = wid >> 1, wave_n = wid & 1;
  const int m0 = blockIdx.x * 128, n0 = blockIdx.y * 128;
  const int quad = lane >> 4, col = lane & 15;

  f32x4 acc[4][4];
#pragma unroll
  for (int i = 0; i < 4; ++i)
#pragma unroll
    for (int j = 0; j < 4; ++j) acc[i][j] = (f32x4){0.f, 0.f, 0.f, 0.f};

  for (int k0 = 0; k0 < 256; k0 += 32) {
#pragma unroll
    for (int h = 0; h < 2; ++h) {
      const int c = tid + h * 256;           // 0..511
      const int r = c >> 2;                  // 0..127
      const int seg = (c & 3) << 3;          // 0,8,16,24
      const int gm = m0 + r;
      uint4 av = make_uint4(0u, 0u, 0u, 0u);
      if (gm < M) av = *(const uint4*)(Ab + (size_t)gm * 256 + k0 + seg);
      *(uint4*)&As[r][seg] = av;
      uint4 bv = *(const uint4*)(Wt + (size_t)(n0 + r) * 256 + k0 + seg);
      *(uint4*)&Bs[r][seg] = bv;
    }
    __syncthreads();

    bf16x8 af[4], bf[4];
#pragma unroll
    for (int i = 0; i < 4; ++i)
      af[i] = *(const bf16x8*)&As[wave_m * 64 + i * 16 + col][quad * 8];
#pragma unroll
    for (int j = 0; j < 4; ++j)
      bf[j] = *(const bf16x8*)&Bs[wave_n * 64 + j * 16 + col][quad * 8];
#pragma unroll
    for (int i = 0; i < 4; ++i)
#pragma unroll
      for (int j = 0; j < 4; ++j)
        acc[i][j] = __builtin_amdgcn_mfma_f32_16x16x32_bf16(af[i], bf[j], acc[i][j], 0, 0, 0);
    __syncthreads();
  }

  // epilogue: C/D layout col=lane&15, row=quad*4+t
#pragma unroll
  for (int i = 0; i < 4; ++i) {
    float dd[4];
    int mbase = m0 + wave_m * 64 + i * 16 + quad * 4;
#pragma unroll
    for (int t = 0; t < 4; ++t) dd[t] = (mbase + t < M) ? dis[mbase + t] : 0.f;
#pragma unroll
    for (int j = 0; j < 4; ++j) {
      const int n = n0 + wave_n * 64 + j * 16 + col;
#pragma unroll
      for (int t = 0; t < 4; ++t) {
        const int m = mbase + t;
        if (m < M) C[(size_t)m * 256 + n] = f2bf(acc[i][j][t] * dd[t]);
      }
    }
  }
}

// ---------------- Aggregate 256-dim bf16: out = relu(dis[d]*(u[d]+sum)+b) -> bf16 ------
__global__ __launch_bounds__(256) void k_agg256(const u16* __restrict__ u,
                                                const int* __restrict__ rs,
                                                const int* __restrict__ csr,
                                                const float* __restrict__ dis,
                                                const float* __restrict__ b,
                                                u16* __restrict__ out, int n) {
  const int wid = threadIdx.x >> 6, lane = threadIdx.x & 63;
  const int d = blockIdx.x * 4 + wid;
  if (d >= n) return;
  const int col = lane << 2;  // 4 bf16 per lane
  uint2 sv = *(const uint2*)(u + (size_t)d * 256 + col);
  float a0 = bfl(sv.x), a1 = bfh(sv.x), a2 = bfl(sv.y), a3 = bfh(sv.y);
  const int p1 = rs[d + 1];
  for (int p = rs[d]; p < p1; ++p) {
    const int s = csr[p];
    const uint2 v = *(const uint2*)(u + (size_t)s * 256 + col);
    a0 += bfl(v.x); a1 += bfh(v.x); a2 += bfl(v.y); a3 += bfh(v.y);
  }
  const float dd = dis[d];
  const float4 bb = *(const float4*)(b + col);
  ushort4 o;
  o.x = f2bf(fmaxf(dd * a0 + bb.x, 0.f));
  o.y = f2bf(fmaxf(dd * a1 + bb.y, 0.f));
  o.z = f2bf(fmaxf(dd * a2 + bb.z, 0.f));
  o.w = f2bf(fmaxf(dd * a3 + bb.w, 0.f));
  *(ushort4*)(out + (size_t)d * 256 + col) = o;
}

// ---------------- GEMM: C[M,40] = A_bf16[M,256] @ W2_f32[256,40], *dis[m] ----------------
__global__ __launch_bounds__(640) void k_gemm40(const u16* __restrict__ A,
                                                const float* __restrict__ W,
                                                const float* __restrict__ dis,
                                                float* __restrict__ C, int M) {
  __shared__ float Ws[256 * 40];
  for (int i = threadIdx.x; i < 256 * 40 / 4; i += 640)
    ((float4*)Ws)[i] = ((const float4*)W)[i];
  __syncthreads();
  const int ng = threadIdx.x % 10;
  const int ml = threadIdx.x / 10;
  const int m = blockIdx.x * 64 + ml;
  if (m >= M) return;
  const u16* __restrict__ arow = A + (size_t)m * 256;
  float4 acc = make_float4(0.f, 0.f, 0.f, 0.f);
  const int nc = ng << 2;
#pragma unroll 2
  for (int k = 0; k < 256; k += 8) {
    const uint4 av = *(const uint4*)(arow + k);
    float a[8] = {bfl(av.x), bfh(av.x), bfl(av.y), bfh(av.y),
                  bfl(av.z), bfh(av.z), bfl(av.w), bfh(av.w)};
#pragma unroll
    for (int kk = 0; kk < 8; ++kk) {
      const float4 w = *(const float4*)&Ws[(k + kk) * 40 + nc];
      acc.x += a[kk] * w.x; acc.y += a[kk] * w.y;
      acc.z += a[kk] * w.z; acc.w += a[kk] * w.w;
    }
  }
  const float dd = dis[m];
  *(float4*)(C + (size_t)m * 40 + nc) =
      make_float4(acc.x * dd, acc.y * dd, acc.z * dd, acc.w * dd);
}

// ---------------- Aggregate 40-dim + bias + log_softmax ----------------
__global__ __launch_bounds__(256) void k_agg40(const float* __restrict__ u,
                                               const int* __restrict__ rs,
                                               const int* __restrict__ csr,
                                               const float* __restrict__ dis,
                                               const float* __restrict__ b,
                                               float* __restrict__ out, int n) {
  const int wid = threadIdx.x >> 6, lane = threadIdx.x & 63;
  const int d = blockIdx.x * 4 + wid;
  if (d >= n) return;
  const bool act = lane < 40;
  float acc = act ? u[(size_t)d * 40 + lane] : 0.f;
  const int p1 = rs[d + 1];
  for (int p = rs[d]; p < p1; ++p) {
    const int s = csr[p];
    if (act) acc += u[(size_t)s * 40 + lane];
  }
  const float logit = act ? dis[d] * acc + b[lane] : -INFINITY;
  float mx = logit;
#pragma unroll
  for (int off = 32; off; off >>= 1) mx = fmaxf(mx, __shfl_xor(mx, off, 64));
  float ex = act ? expf(logit - mx) : 0.f;
  float sm = ex;
#pragma unroll
  for (int off = 32; off; off >>= 1) sm += __shfl_xor(sm, off, 64);
  if (act) out[(size_t)d * 40 + lane] = logit - mx - logf(sm);
}

// ---------------- launch ----------------
extern "C" void kernel_launch(void* const* d_in, const int* in_sizes, int n_in,
                              void* d_out, int out_size, void* d_ws, size_t ws_size,
                              hipStream_t stream) {
  const float* x  = (const float*)d_in[0];
  const int*   ei = (const int*)d_in[1];
  const float* W0 = (const float*)d_in[2];
  const float* b0 = (const float*)d_in[3];
  const float* W1 = (const float*)d_in[4];
  const float* b1 = (const float*)d_in[5];
  const float* W2 = (const float*)d_in[6];
  const float* b2 = (const float*)d_in[7];
  float* out = (float*)d_out;

  const int N = in_sizes[0] / 256;
  const int E = in_sizes[1] / 2;
  const int* src = ei;
  const int* dst = ei + E;

  char* p = (char*)d_ws;
  auto carve = [&](size_t bytes) {
    char* q = p;
    p += (bytes + 255) & ~(size_t)255;
    return q;
  };
  u16*   xb   = (u16*)carve((size_t)N * 256 * 2);
  u16*   bufU = (u16*)carve((size_t)N * 256 * 2);
  u16*   bufH = (u16*)carve((size_t)N * 256 * 2);
  float* u40  = (float*)carve((size_t)N * 40 * 4);
  u16*   Wt0  = (u16*)carve(256 * 256 * 2);
  u16*   Wt1  = (u16*)carve(256 * 256 * 2);
  float* dis  = (float*)carve((size_t)N * 4);
  int*   cnt  = (int*)carve((size_t)N * 4);
  int*   rs   = (int*)carve((size_t)(N + 1) * 4);
  int*   cur  = (int*)carve((size_t)N * 4);
  int*   csr  = (int*)carve((size_t)E * 4);
  int*   bsum = (int*)carve(1024 * 4);

  // CSR + deg: count -> 3-phase hierarchical scan -> fill
  hipMemsetAsync(cnt, 0, (size_t)N * 4, stream);
  const int eb = (E + 255) / 256;
  const int nb = (N + 1023) / 1024;
  k_count<<<eb, 256, 0, stream>>>(dst, cnt, E);
  k_scan1<<<nb, 1024, 0, stream>>>(cnt, rs, dis, bsum, N);
  k_scan2<<<1, 64, 0, stream>>>(bsum, rs, nb, N);
  k_scan3<<<nb, 1024, 0, stream>>>(rs, cur, bsum, N);
  k_fill<<<eb, 256, 0, stream>>>(src, dst, cur, csr, E);

  // converts
  k_cvt<<<(N * 64 + 255) / 256, 256, 0, stream>>>(x, xb, N * 64);
  k_prepw<<<256, 256, 0, stream>>>(W0, Wt0);
  k_prepw<<<256, 256, 0, stream>>>(W1, Wt1);

  const dim3 ggrid((N + 127) / 128, 2);
  const int agrid = (N + 3) / 4;

  // layer 0
  k_gemm256<<<ggrid, 256, 0, stream>>>(xb, Wt0, dis, bufU, N);
  k_agg256<<<agrid, 256, 0, stream>>>(bufU, rs, csr, dis, b0, bufH, N);
  // layer 1
  k_gemm256<<<ggrid, 256, 0, stream>>>(bufH, Wt1, dis, bufU, N);
  k_agg256<<<agrid, 256, 0, stream>>>(bufU, rs, csr, dis, b1, bufH, N);
  // layer 2
  k_gemm40<<<(N + 63) / 64, 640, 0, stream>>>(bufH, W2, dis, u40, N);
  k_agg40<<<agrid, 256, 0, stream>>>(u40, rs, csr, dis, b2, out, N);
}

// Round 4
// 447.418 us; speedup vs baseline: 1.7266x; 1.2557x over previous
//
#include <hip/hip_runtime.h>
#include <hip/hip_bf16.h>
#include <cstdint>
#include <cstddef>

// GCN 3-layer forward, MI355X (gfx950).
// Round 4: 4-way unrolled neighbor gather in aggregation kernels (round-3
// profile: agg256 latency-bound at 29% HBM / 19% VALU -> serial per-edge
// dependent-load chain). Scan/GEMM unchanged.

typedef unsigned short u16;
typedef unsigned int u32;
typedef __attribute__((ext_vector_type(8))) short bf16x8;
typedef __attribute__((ext_vector_type(4))) float f32x4;

__device__ inline float bfl(u32 u) { return __uint_as_float(u << 16); }
__device__ inline float bfh(u32 u) { return __uint_as_float(u & 0xffff0000u); }
__device__ inline u16 f2bf(float f) {
  __hip_bfloat16 h = __float2bfloat16(f);
  return __builtin_bit_cast(u16, h);
}

// ---------------- CSR build ----------------
__global__ void k_count(const int* __restrict__ dst, int* __restrict__ cnt, int E) {
  int e = blockIdx.x * blockDim.x + threadIdx.x;
  if (e < E) atomicAdd(&cnt[dst[e]], 1);
}

// phase 1: per-block exclusive scan (1024 elems/block) + block total + dis
__global__ __launch_bounds__(1024) void k_scan1(const int* __restrict__ cnt,
                                                int* __restrict__ rs,
                                                float* __restrict__ dis,
                                                int* __restrict__ bsum, int n) {
  __shared__ int wsum[16];
  const int tid = threadIdx.x;
  const int lane = tid & 63, wid = tid >> 6;
  const int i = blockIdx.x * 1024 + tid;
  const int v = (i < n) ? cnt[i] : 0;
  int x = v;
#pragma unroll
  for (int off = 1; off < 64; off <<= 1) {
    int y = __shfl_up(x, off, 64);
    if (lane >= off) x += y;
  }
  if (lane == 63) wsum[wid] = x;
  __syncthreads();
  if (wid == 0) {
    int w = (lane < 16) ? wsum[lane] : 0;
#pragma unroll
    for (int off = 1; off < 16; off <<= 1) {
      int y = __shfl_up(w, off, 64);
      if (lane >= off) w += y;
    }
    if (lane < 16) wsum[lane] = w;
  }
  __syncthreads();
  const int excl = (wid > 0 ? wsum[wid - 1] : 0) + (x - v);
  if (i < n) {
    rs[i] = excl;
    dis[i] = rsqrtf((float)(1 + v));
  }
  if (tid == 0) bsum[blockIdx.x] = wsum[15];
}

// phase 2: scan the block sums, write grand total to rs[n]
__global__ __launch_bounds__(64) void k_scan2(int* __restrict__ bsum,
                                              int* __restrict__ rs, int nb, int n) {
  const int lane = threadIdx.x;
  int carry = 0;
  for (int base = 0; base < nb; base += 64) {
    const int j = base + lane;
    const int v = (j < nb) ? bsum[j] : 0;
    int x = v;
#pragma unroll
    for (int off = 1; off < 64; off <<= 1) {
      int y = __shfl_up(x, off, 64);
      if (lane >= off) x += y;
    }
    if (j < nb) bsum[j] = carry + (x - v);  // exclusive
    carry += __shfl(x, 63, 64);
  }
  if (lane == 0) rs[n] = carry;
}

// phase 3: add block offsets, write cur
__global__ __launch_bounds__(1024) void k_scan3(int* __restrict__ rs,
                                                int* __restrict__ cur,
                                                const int* __restrict__ bsum, int n) {
  const int i = blockIdx.x * 1024 + threadIdx.x;
  if (i < n) {
    const int r = rs[i] + bsum[blockIdx.x];
    rs[i] = r;
    cur[i] = r;
  }
}

__global__ void k_fill(const int* __restrict__ src, const int* __restrict__ dst,
                       int* __restrict__ cur, int* __restrict__ csr, int E) {
  int e = blockIdx.x * blockDim.x + threadIdx.x;
  if (e < E) {
    int p = atomicAdd(&cur[dst[e]], 1);
    csr[p] = src[e];
  }
}

// ---------------- converts ----------------
__global__ void k_cvt(const float* __restrict__ x, u16* __restrict__ xb, int total4) {
  int i = blockIdx.x * blockDim.x + threadIdx.x;
  if (i < total4) {
    float4 v = ((const float4*)x)[i];
    ushort4 o;
    o.x = f2bf(v.x); o.y = f2bf(v.y); o.z = f2bf(v.z); o.w = f2bf(v.w);
    ((ushort4*)xb)[i] = o;
  }
}

// Wt[n][k] = bf16(W[k][n]), 256x256
__global__ void k_prepw(const float* __restrict__ W, u16* __restrict__ Wt) {
  int t = blockIdx.x * 256 + threadIdx.x;
  int k = t >> 8, n = t & 255;
  Wt[n * 256 + k] = f2bf(W[t]);
}

// ---------------- MFMA GEMM: C[M,256] = A[M,256] @ W, epilogue *dis[m], bf16 out ----------
// 128x128 block tile, 4 waves (2x2), each wave 64x64 (4x4 of 16x16x32 MFMA), BK=32.
__global__ __launch_bounds__(256) void k_gemm256(const u16* __restrict__ Ab,
                                                 const u16* __restrict__ Wt,
                                                 const float* __restrict__ dis,
                                                 u16* __restrict__ C, int M) {
  __shared__ u16 As[128][40];  // stride 40 bf16 = 80B: 16B-aligned, 2-way banks (free)
  __shared__ u16 Bs[128][40];
  const int tid = threadIdx.x;
  const int wid = tid >> 6, lane = tid & 63;
  const int wave_m = wid >> 1, wave_n = wid & 1;
  const int m0 = blockIdx.x * 128, n0 = blockIdx.y * 128;
  const int quad = lane >> 4, col = lane & 15;

  f32x4 acc[4][4];
#pragma unroll
  for (int i = 0; i < 4; ++i)
#pragma unroll
    for (int j = 0; j < 4; ++j) acc[i][j] = (f32x4){0.f, 0.f, 0.f, 0.f};

  for (int k0 = 0; k0 < 256; k0 += 32) {
#pragma unroll
    for (int h = 0; h < 2; ++h) {
      const int c = tid + h * 256;           // 0..511
      const int r = c >> 2;                  // 0..127
      const int seg = (c & 3) << 3;          // 0,8,16,24
      const int gm = m0 + r;
      uint4 av = make_uint4(0u, 0u, 0u, 0u);
      if (gm < M) av = *(const uint4*)(Ab + (size_t)gm * 256 + k0 + seg);
      *(uint4*)&As[r][seg] = av;
      uint4 bv = *(const uint4*)(Wt + (size_t)(n0 + r) * 256 + k0 + seg);
      *(uint4*)&Bs[r][seg] = bv;
    }
    __syncthreads();

    bf16x8 af[4], bf[4];
#pragma unroll
    for (int i = 0; i < 4; ++i)
      af[i] = *(const bf16x8*)&As[wave_m * 64 + i * 16 + col][quad * 8];
#pragma unroll
    for (int j = 0; j < 4; ++j)
      bf[j] = *(const bf16x8*)&Bs[wave_n * 64 + j * 16 + col][quad * 8];
#pragma unroll
    for (int i = 0; i < 4; ++i)
#pragma unroll
      for (int j = 0; j < 4; ++j)
        acc[i][j] = __builtin_amdgcn_mfma_f32_16x16x32_bf16(af[i], bf[j], acc[i][j], 0, 0, 0);
    __syncthreads();
  }

  // epilogue: C/D layout col=lane&15, row=quad*4+t
#pragma unroll
  for (int i = 0; i < 4; ++i) {
    float dd[4];
    int mbase = m0 + wave_m * 64 + i * 16 + quad * 4;
#pragma unroll
    for (int t = 0; t < 4; ++t) dd[t] = (mbase + t < M) ? dis[mbase + t] : 0.f;
#pragma unroll
    for (int j = 0; j < 4; ++j) {
      const int n = n0 + wave_n * 64 + j * 16 + col;
#pragma unroll
      for (int t = 0; t < 4; ++t) {
        const int m = mbase + t;
        if (m < M) C[(size_t)m * 256 + n] = f2bf(acc[i][j][t] * dd[t]);
      }
    }
  }
}

// ---------------- Aggregate 256-dim bf16, 4-way unrolled gather ----------------
__global__ __launch_bounds__(256) void k_agg256(const u16* __restrict__ u,
                                                const int* __restrict__ rs,
                                                const int* __restrict__ csr,
                                                const float* __restrict__ dis,
                                                const float* __restrict__ b,
                                                u16* __restrict__ out, int n) {
  const int wid = threadIdx.x >> 6, lane = threadIdx.x & 63;
  const int d = blockIdx.x * 4 + wid;
  if (d >= n) return;
  const int col = lane << 2;  // 4 bf16 per lane
  uint2 sv = *(const uint2*)(u + (size_t)d * 256 + col);
  float a0 = bfl(sv.x), a1 = bfh(sv.x), a2 = bfl(sv.y), a3 = bfh(sv.y);
  int p = rs[d];
  const int p1 = rs[d + 1];
  // 4 independent row loads in flight per iteration
  for (; p + 4 <= p1; p += 4) {
    const int s0 = csr[p + 0], s1 = csr[p + 1], s2 = csr[p + 2], s3 = csr[p + 3];
    const uint2 v0 = *(const uint2*)(u + (size_t)s0 * 256 + col);
    const uint2 v1 = *(const uint2*)(u + (size_t)s1 * 256 + col);
    const uint2 v2 = *(const uint2*)(u + (size_t)s2 * 256 + col);
    const uint2 v3 = *(const uint2*)(u + (size_t)s3 * 256 + col);
    a0 += bfl(v0.x) + bfl(v1.x) + bfl(v2.x) + bfl(v3.x);
    a1 += bfh(v0.x) + bfh(v1.x) + bfh(v2.x) + bfh(v3.x);
    a2 += bfl(v0.y) + bfl(v1.y) + bfl(v2.y) + bfl(v3.y);
    a3 += bfh(v0.y) + bfh(v1.y) + bfh(v2.y) + bfh(v3.y);
  }
  for (; p < p1; ++p) {
    const int s = csr[p];
    const uint2 v = *(const uint2*)(u + (size_t)s * 256 + col);
    a0 += bfl(v.x); a1 += bfh(v.x); a2 += bfl(v.y); a3 += bfh(v.y);
  }
  const float dd = dis[d];
  const float4 bb = *(const float4*)(b + col);
  ushort4 o;
  o.x = f2bf(fmaxf(dd * a0 + bb.x, 0.f));
  o.y = f2bf(fmaxf(dd * a1 + bb.y, 0.f));
  o.z = f2bf(fmaxf(dd * a2 + bb.z, 0.f));
  o.w = f2bf(fmaxf(dd * a3 + bb.w, 0.f));
  *(ushort4*)(out + (size_t)d * 256 + col) = o;
}

// ---------------- GEMM: C[M,40] = A_bf16[M,256] @ W2_f32[256,40], *dis[m] ----------------
__global__ __launch_bounds__(640) void k_gemm40(const u16* __restrict__ A,
                                                const float* __restrict__ W,
                                                const float* __restrict__ dis,
                                                float* __restrict__ C, int M) {
  __shared__ float Ws[256 * 40];
  for (int i = threadIdx.x; i < 256 * 40 / 4; i += 640)
    ((float4*)Ws)[i] = ((const float4*)W)[i];
  __syncthreads();
  const int ng = threadIdx.x % 10;
  const int ml = threadIdx.x / 10;
  const int m = blockIdx.x * 64 + ml;
  if (m >= M) return;
  const u16* __restrict__ arow = A + (size_t)m * 256;
  float4 acc = make_float4(0.f, 0.f, 0.f, 0.f);
  const int nc = ng << 2;
#pragma unroll 2
  for (int k = 0; k < 256; k += 8) {
    const uint4 av = *(const uint4*)(arow + k);
    float a[8] = {bfl(av.x), bfh(av.x), bfl(av.y), bfh(av.y),
                  bfl(av.z), bfh(av.z), bfl(av.w), bfh(av.w)};
#pragma unroll
    for (int kk = 0; kk < 8; ++kk) {
      const float4 w = *(const float4*)&Ws[(k + kk) * 40 + nc];
      acc.x += a[kk] * w.x; acc.y += a[kk] * w.y;
      acc.z += a[kk] * w.z; acc.w += a[kk] * w.w;
    }
  }
  const float dd = dis[m];
  *(float4*)(C + (size_t)m * 40 + nc) =
      make_float4(acc.x * dd, acc.y * dd, acc.z * dd, acc.w * dd);
}

// ---------------- Aggregate 40-dim + bias + log_softmax, 4-way unrolled ----------------
__global__ __launch_bounds__(256) void k_agg40(const float* __restrict__ u,
                                               const int* __restrict__ rs,
                                               const int* __restrict__ csr,
                                               const float* __restrict__ dis,
                                               const float* __restrict__ b,
                                               float* __restrict__ out, int n) {
  const int wid = threadIdx.x >> 6, lane = threadIdx.x & 63;
  const int d = blockIdx.x * 4 + wid;
  if (d >= n) return;
  const bool act = lane < 40;
  const int cl = act ? lane : 0;
  float acc = act ? u[(size_t)d * 40 + lane] : 0.f;
  int p = rs[d];
  const int p1 = rs[d + 1];
  for (; p + 4 <= p1; p += 4) {
    const int s0 = csr[p + 0], s1 = csr[p + 1], s2 = csr[p + 2], s3 = csr[p + 3];
    const float v0 = u[(size_t)s0 * 40 + cl];
    const float v1 = u[(size_t)s1 * 40 + cl];
    const float v2 = u[(size_t)s2 * 40 + cl];
    const float v3 = u[(size_t)s3 * 40 + cl];
    if (act) acc += v0 + v1 + v2 + v3;
  }
  for (; p < p1; ++p) {
    const int s = csr[p];
    const float v = u[(size_t)s * 40 + cl];
    if (act) acc += v;
  }
  const float logit = act ? dis[d] * acc + b[lane] : -INFINITY;
  float mx = logit;
#pragma unroll
  for (int off = 32; off; off >>= 1) mx = fmaxf(mx, __shfl_xor(mx, off, 64));
  float ex = act ? expf(logit - mx) : 0.f;
  float sm = ex;
#pragma unroll
  for (int off = 32; off; off >>= 1) sm += __shfl_xor(sm, off, 64);
  if (act) out[(size_t)d * 40 + lane] = logit - mx - logf(sm);
}

// ---------------- launch ----------------
extern "C" void kernel_launch(void* const* d_in, const int* in_sizes, int n_in,
                              void* d_out, int out_size, void* d_ws, size_t ws_size,
                              hipStream_t stream) {
  const float* x  = (const float*)d_in[0];
  const int*   ei = (const int*)d_in[1];
  const float* W0 = (const float*)d_in[2];
  const float* b0 = (const float*)d_in[3];
  const float* W1 = (const float*)d_in[4];
  const float* b1 = (const float*)d_in[5];
  const float* W2 = (const float*)d_in[6];
  const float* b2 = (const float*)d_in[7];
  float* out = (float*)d_out;

  const int N = in_sizes[0] / 256;
  const int E = in_sizes[1] / 2;
  const int* src = ei;
  const int* dst = ei + E;

  char* p = (char*)d_ws;
  auto carve = [&](size_t bytes) {
    char* q = p;
    p += (bytes + 255) & ~(size_t)255;
    return q;
  };
  u16*   xb   = (u16*)carve((size_t)N * 256 * 2);
  u16*   bufU = (u16*)carve((size_t)N * 256 * 2);
  u16*   bufH = (u16*)carve((size_t)N * 256 * 2);
  float* u40  = (float*)carve((size_t)N * 40 * 4);
  u16*   Wt0  = (u16*)carve(256 * 256 * 2);
  u16*   Wt1  = (u16*)carve(256 * 256 * 2);
  float* dis  = (float*)carve((size_t)N * 4);
  int*   cnt  = (int*)carve((size_t)N * 4);
  int*   rs   = (int*)carve((size_t)(N + 1) * 4);
  int*   cur  = (int*)carve((size_t)N * 4);
  int*   csr  = (int*)carve((size_t)E * 4);
  int*   bsum = (int*)carve(1024 * 4);

  // CSR + deg: count -> 3-phase hierarchical scan -> fill
  hipMemsetAsync(cnt, 0, (size_t)N * 4, stream);
  const int eb = (E + 255) / 256;
  const int nb = (N + 1023) / 1024;
  k_count<<<eb, 256, 0, stream>>>(dst, cnt, E);
  k_scan1<<<nb, 1024, 0, stream>>>(cnt, rs, dis, bsum, N);
  k_scan2<<<1, 64, 0, stream>>>(bsum, rs, nb, N);
  k_scan3<<<nb, 1024, 0, stream>>>(rs, cur, bsum, N);
  k_fill<<<eb, 256, 0, stream>>>(src, dst, cur, csr, E);

  // converts
  k_cvt<<<(N * 64 + 255) / 256, 256, 0, stream>>>(x, xb, N * 64);
  k_prepw<<<256, 256, 0, stream>>>(W0, Wt0);
  k_prepw<<<256, 256, 0, stream>>>(W1, Wt1);

  const dim3 ggrid((N + 127) / 128, 2);
  const int agrid = (N + 3) / 4;

  // layer 0
  k_gemm256<<<ggrid, 256, 0, stream>>>(xb, Wt0, dis, bufU, N);
  k_agg256<<<agrid, 256, 0, stream>>>(bufU, rs, csr, dis, b0, bufH, N);
  // layer 1
  k_gemm256<<<ggrid, 256, 0, stream>>>(bufH, Wt1, dis, bufU, N);
  k_agg256<<<agrid, 256, 0, stream>>>(bufU, rs, csr, dis, b1, bufH, N);
  // layer 2
  k_gemm40<<<(N + 63) / 64, 640, 0, stream>>>(bufH, W2, dis, u40, N);
  k_agg40<<<agrid, 256, 0, stream>>>(u40, rs, csr, dis, b2, out, N);
}

// Round 5
// 443.702 us; speedup vs baseline: 1.7410x; 1.0084x over previous
//
#include <hip/hip_runtime.h>
#include <hip/hip_bf16.h>
#include <cstdint>
#include <cstddef>

// GCN 3-layer forward, MI355X (gfx950).
// Round 5: 8-way gather unroll + zero-row tail padding in agg kernels
// (round-4: agg256 still latency-bound at 45% HBM / 29% VALU with 4-way);
// layer-0 GEMM reads fp32 x directly (k_cvt eliminated).

typedef unsigned short u16;
typedef unsigned int u32;
typedef __attribute__((ext_vector_type(8))) short bf16x8;
typedef __attribute__((ext_vector_type(4))) float f32x4;

__device__ inline float bfl(u32 u) { return __uint_as_float(u << 16); }
__device__ inline float bfh(u32 u) { return __uint_as_float(u & 0xffff0000u); }
__device__ inline u16 f2bf(float f) {
  __hip_bfloat16 h = __float2bfloat16(f);
  return __builtin_bit_cast(u16, h);
}

// ---------------- CSR build ----------------
__global__ void k_count(const int* __restrict__ dst, int* __restrict__ cnt, int E) {
  int e = blockIdx.x * blockDim.x + threadIdx.x;
  if (e < E) atomicAdd(&cnt[dst[e]], 1);
}

__global__ __launch_bounds__(1024) void k_scan1(const int* __restrict__ cnt,
                                                int* __restrict__ rs,
                                                float* __restrict__ dis,
                                                int* __restrict__ bsum, int n) {
  __shared__ int wsum[16];
  const int tid = threadIdx.x;
  const int lane = tid & 63, wid = tid >> 6;
  const int i = blockIdx.x * 1024 + tid;
  const int v = (i < n) ? cnt[i] : 0;
  int x = v;
#pragma unroll
  for (int off = 1; off < 64; off <<= 1) {
    int y = __shfl_up(x, off, 64);
    if (lane >= off) x += y;
  }
  if (lane == 63) wsum[wid] = x;
  __syncthreads();
  if (wid == 0) {
    int w = (lane < 16) ? wsum[lane] : 0;
#pragma unroll
    for (int off = 1; off < 16; off <<= 1) {
      int y = __shfl_up(w, off, 64);
      if (lane >= off) w += y;
    }
    if (lane < 16) wsum[lane] = w;
  }
  __syncthreads();
  const int excl = (wid > 0 ? wsum[wid - 1] : 0) + (x - v);
  if (i < n) {
    rs[i] = excl;
    dis[i] = rsqrtf((float)(1 + v));
  }
  if (tid == 0) bsum[blockIdx.x] = wsum[15];
}

__global__ __launch_bounds__(64) void k_scan2(int* __restrict__ bsum,
                                              int* __restrict__ rs, int nb, int n) {
  const int lane = threadIdx.x;
  int carry = 0;
  for (int base = 0; base < nb; base += 64) {
    const int j = base + lane;
    const int v = (j < nb) ? bsum[j] : 0;
    int x = v;
#pragma unroll
    for (int off = 1; off < 64; off <<= 1) {
      int y = __shfl_up(x, off, 64);
      if (lane >= off) x += y;
    }
    if (j < nb) bsum[j] = carry + (x - v);
    carry += __shfl(x, 63, 64);
  }
  if (lane == 0) rs[n] = carry;
}

__global__ __launch_bounds__(1024) void k_scan3(int* __restrict__ rs,
                                                int* __restrict__ cur,
                                                const int* __restrict__ bsum, int n) {
  const int i = blockIdx.x * 1024 + threadIdx.x;
  if (i < n) {
    const int r = rs[i] + bsum[blockIdx.x];
    rs[i] = r;
    cur[i] = r;
  }
}

__global__ void k_fill(const int* __restrict__ src, const int* __restrict__ dst,
                       int* __restrict__ cur, int* __restrict__ csr, int E) {
  int e = blockIdx.x * blockDim.x + threadIdx.x;
  if (e < E) {
    int p = atomicAdd(&cur[dst[e]], 1);
    csr[p] = src[e];
  }
}

// Wt[n][k] = bf16(W[k][n]), 256x256
__global__ void k_prepw(const float* __restrict__ W, u16* __restrict__ Wt) {
  int t = blockIdx.x * 256 + threadIdx.x;
  int k = t >> 8, n = t & 255;
  Wt[n * 256 + k] = f2bf(W[t]);
}

// ---------------- MFMA GEMM: C[M,256] = A[M,256] @ W, epilogue *dis[m], bf16 out ----------
// A is fp32 (layer 0, converted during staging) or bf16. 128x128 tile, 4 waves,
// each wave 64x64 (4x4 of 16x16x32 MFMA), BK=32. LDS stride 40 (2-way banks, free).
template <bool F32A>
__global__ __launch_bounds__(256) void k_gemm256(const void* __restrict__ Aptr,
                                                 const u16* __restrict__ Wt,
                                                 const float* __restrict__ dis,
                                                 u16* __restrict__ C, int M) {
  __shared__ u16 As[128][40];
  __shared__ u16 Bs[128][40];
  const int tid = threadIdx.x;
  const int wid = tid >> 6, lane = tid & 63;
  const int wave_m = wid >> 1, wave_n = wid & 1;
  const int m0 = blockIdx.x * 128, n0 = blockIdx.y * 128;
  const int quad = lane >> 4, col = lane & 15;

  f32x4 acc[4][4];
#pragma unroll
  for (int i = 0; i < 4; ++i)
#pragma unroll
    for (int j = 0; j < 4; ++j) acc[i][j] = (f32x4){0.f, 0.f, 0.f, 0.f};

  for (int k0 = 0; k0 < 256; k0 += 32) {
#pragma unroll
    for (int h = 0; h < 2; ++h) {
      const int c = tid + h * 256;           // 0..511
      const int r = c >> 2;                  // 0..127
      const int seg = (c & 3) << 3;          // 0,8,16,24
      const int gm = m0 + r;
      if (F32A) {
        const float* A = (const float*)Aptr;
        float4 lo = make_float4(0.f, 0.f, 0.f, 0.f), hi = lo;
        if (gm < M) {
          lo = *(const float4*)(A + (size_t)gm * 256 + k0 + seg);
          hi = *(const float4*)(A + (size_t)gm * 256 + k0 + seg + 4);
        }
        ushort4 q0, q1;
        q0.x = f2bf(lo.x); q0.y = f2bf(lo.y); q0.z = f2bf(lo.z); q0.w = f2bf(lo.w);
        q1.x = f2bf(hi.x); q1.y = f2bf(hi.y); q1.z = f2bf(hi.z); q1.w = f2bf(hi.w);
        *(ushort4*)&As[r][seg] = q0;
        *(ushort4*)&As[r][seg + 4] = q1;
      } else {
        const u16* A = (const u16*)Aptr;
        uint4 av = make_uint4(0u, 0u, 0u, 0u);
        if (gm < M) av = *(const uint4*)(A + (size_t)gm * 256 + k0 + seg);
        *(uint4*)&As[r][seg] = av;
      }
      uint4 bv = *(const uint4*)(Wt + (size_t)(n0 + r) * 256 + k0 + seg);
      *(uint4*)&Bs[r][seg] = bv;
    }
    __syncthreads();

    bf16x8 af[4], bf[4];
#pragma unroll
    for (int i = 0; i < 4; ++i)
      af[i] = *(const bf16x8*)&As[wave_m * 64 + i * 16 + col][quad * 8];
#pragma unroll
    for (int j = 0; j < 4; ++j)
      bf[j] = *(const bf16x8*)&Bs[wave_n * 64 + j * 16 + col][quad * 8];
#pragma unroll
    for (int i = 0; i < 4; ++i)
#pragma unroll
      for (int j = 0; j < 4; ++j)
        acc[i][j] = __builtin_amdgcn_mfma_f32_16x16x32_bf16(af[i], bf[j], acc[i][j], 0, 0, 0);
    __syncthreads();
  }

  // epilogue: C/D layout col=lane&15, row=quad*4+t
#pragma unroll
  for (int i = 0; i < 4; ++i) {
    float dd[4];
    int mbase = m0 + wave_m * 64 + i * 16 + quad * 4;
#pragma unroll
    for (int t = 0; t < 4; ++t) dd[t] = (mbase + t < M) ? dis[mbase + t] : 0.f;
#pragma unroll
    for (int j = 0; j < 4; ++j) {
      const int n = n0 + wave_n * 64 + j * 16 + col;
#pragma unroll
      for (int t = 0; t < 4; ++t) {
        const int m = mbase + t;
        if (m < M) C[(size_t)m * 256 + n] = f2bf(acc[i][j][t] * dd[t]);
      }
    }
  }
}

// ---------------- Aggregate 256-dim bf16, 8-way unrolled (zero-row tail pad) --------
__global__ __launch_bounds__(256) void k_agg256(const u16* __restrict__ u,
                                                const int* __restrict__ rs,
                                                const int* __restrict__ csr,
                                                const float* __restrict__ dis,
                                                const float* __restrict__ b,
                                                u16* __restrict__ out, int n) {
  const int wid = threadIdx.x >> 6, lane = threadIdx.x & 63;
  const int d = blockIdx.x * 4 + wid;
  if (d >= n) return;
  const int col = lane << 2;  // 4 bf16 per lane
  uint2 sv = *(const uint2*)(u + (size_t)d * 256 + col);
  float a0 = bfl(sv.x), a1 = bfh(sv.x), a2 = bfl(sv.y), a3 = bfh(sv.y);
  const int p1 = rs[d + 1];
  for (int p = rs[d]; p < p1; p += 8) {
    int idx[8];
#pragma unroll
    for (int i = 0; i < 8; ++i) idx[i] = (p + i < p1) ? csr[p + i] : n;  // row n = zeros
    uint2 v[8];
#pragma unroll
    for (int i = 0; i < 8; ++i) v[i] = *(const uint2*)(u + (size_t)idx[i] * 256 + col);
#pragma unroll
    for (int i = 0; i < 8; ++i) {
      a0 += bfl(v[i].x); a1 += bfh(v[i].x);
      a2 += bfl(v[i].y); a3 += bfh(v[i].y);
    }
  }
  const float dd = dis[d];
  const float4 bb = *(const float4*)(b + col);
  ushort4 o;
  o.x = f2bf(fmaxf(dd * a0 + bb.x, 0.f));
  o.y = f2bf(fmaxf(dd * a1 + bb.y, 0.f));
  o.z = f2bf(fmaxf(dd * a2 + bb.z, 0.f));
  o.w = f2bf(fmaxf(dd * a3 + bb.w, 0.f));
  *(ushort4*)(out + (size_t)d * 256 + col) = o;
}

// ---------------- GEMM: C[M,40] = A_bf16[M,256] @ W2_f32[256,40], *dis[m] ----------------
__global__ __launch_bounds__(640) void k_gemm40(const u16* __restrict__ A,
                                                const float* __restrict__ W,
                                                const float* __restrict__ dis,
                                                float* __restrict__ C, int M) {
  __shared__ float Ws[256 * 40];
  for (int i = threadIdx.x; i < 256 * 40 / 4; i += 640)
    ((float4*)Ws)[i] = ((const float4*)W)[i];
  __syncthreads();
  const int ng = threadIdx.x % 10;
  const int ml = threadIdx.x / 10;
  const int m = blockIdx.x * 64 + ml;
  if (m >= M) return;
  const u16* __restrict__ arow = A + (size_t)m * 256;
  float4 acc = make_float4(0.f, 0.f, 0.f, 0.f);
  const int nc = ng << 2;
#pragma unroll 2
  for (int k = 0; k < 256; k += 8) {
    const uint4 av = *(const uint4*)(arow + k);
    float a[8] = {bfl(av.x), bfh(av.x), bfl(av.y), bfh(av.y),
                  bfl(av.z), bfh(av.z), bfl(av.w), bfh(av.w)};
#pragma unroll
    for (int kk = 0; kk < 8; ++kk) {
      const float4 w = *(const float4*)&Ws[(k + kk) * 40 + nc];
      acc.x += a[kk] * w.x; acc.y += a[kk] * w.y;
      acc.z += a[kk] * w.z; acc.w += a[kk] * w.w;
    }
  }
  const float dd = dis[m];
  *(float4*)(C + (size_t)m * 40 + nc) =
      make_float4(acc.x * dd, acc.y * dd, acc.z * dd, acc.w * dd);
}

// ---------------- Aggregate 40-dim + bias + log_softmax, 8-way unrolled ----------------
__global__ __launch_bounds__(256) void k_agg40(const float* __restrict__ u,
                                               const int* __restrict__ rs,
                                               const int* __restrict__ csr,
                                               const float* __restrict__ dis,
                                               const float* __restrict__ b,
                                               float* __restrict__ out, int n) {
  const int wid = threadIdx.x >> 6, lane = threadIdx.x & 63;
  const int d = blockIdx.x * 4 + wid;
  if (d >= n) return;
  const bool act = lane < 40;
  const int cl = act ? lane : 0;
  float acc = act ? u[(size_t)d * 40 + lane] : 0.f;
  const int p1 = rs[d + 1];
  for (int p = rs[d]; p < p1; p += 8) {
    int idx[8];
#pragma unroll
    for (int i = 0; i < 8; ++i) idx[i] = (p + i < p1) ? csr[p + i] : n;  // row n = zeros
    float v[8];
#pragma unroll
    for (int i = 0; i < 8; ++i) v[i] = u[(size_t)idx[i] * 40 + cl];
    float s = 0.f;
#pragma unroll
    for (int i = 0; i < 8; ++i) s += v[i];
    if (act) acc += s;
  }
  const float logit = act ? dis[d] * acc + b[lane] : -INFINITY;
  float mx = logit;
#pragma unroll
  for (int off = 32; off; off >>= 1) mx = fmaxf(mx, __shfl_xor(mx, off, 64));
  float ex = act ? expf(logit - mx) : 0.f;
  float sm = ex;
#pragma unroll
  for (int off = 32; off; off >>= 1) sm += __shfl_xor(sm, off, 64);
  if (act) out[(size_t)d * 40 + lane] = logit - mx - logf(sm);
}

// ---------------- launch ----------------
extern "C" void kernel_launch(void* const* d_in, const int* in_sizes, int n_in,
                              void* d_out, int out_size, void* d_ws, size_t ws_size,
                              hipStream_t stream) {
  const float* x  = (const float*)d_in[0];
  const int*   ei = (const int*)d_in[1];
  const float* W0 = (const float*)d_in[2];
  const float* b0 = (const float*)d_in[3];
  const float* W1 = (const float*)d_in[4];
  const float* b1 = (const float*)d_in[5];
  const float* W2 = (const float*)d_in[6];
  const float* b2 = (const float*)d_in[7];
  float* out = (float*)d_out;

  const int N = in_sizes[0] / 256;
  const int E = in_sizes[1] / 2;
  const int* src = ei;
  const int* dst = ei + E;

  char* p = (char*)d_ws;
  auto carve = [&](size_t bytes) {
    char* q = p;
    p += (bytes + 255) & ~(size_t)255;
    return q;
  };
  u16*   bufU = (u16*)carve((size_t)(N + 1) * 256 * 2);  // +1 zero row for tail pad
  u16*   bufH = (u16*)carve((size_t)(N + 1) * 256 * 2);
  float* u40  = (float*)carve((size_t)(N + 1) * 40 * 4);
  u16*   Wt0  = (u16*)carve(256 * 256 * 2);
  u16*   Wt1  = (u16*)carve(256 * 256 * 2);
  float* dis  = (float*)carve((size_t)N * 4);
  int*   cnt  = (int*)carve((size_t)N * 4);
  int*   rs   = (int*)carve((size_t)(N + 1) * 4);
  int*   cur  = (int*)carve((size_t)N * 4);
  int*   csr  = (int*)carve((size_t)(E + 8) * 4);
  int*   bsum = (int*)carve(1024 * 4);

  // zero rows for gather tail padding + cnt init
  hipMemsetAsync(cnt, 0, (size_t)N * 4, stream);
  hipMemsetAsync(bufU + (size_t)N * 256, 0, 512, stream);
  hipMemsetAsync(bufH + (size_t)N * 256, 0, 512, stream);
  hipMemsetAsync(u40 + (size_t)N * 40, 0, 160, stream);

  // CSR + deg: count -> 3-phase hierarchical scan -> fill
  const int eb = (E + 255) / 256;
  const int nb = (N + 1023) / 1024;
  k_count<<<eb, 256, 0, stream>>>(dst, cnt, E);
  k_scan1<<<nb, 1024, 0, stream>>>(cnt, rs, dis, bsum, N);
  k_scan2<<<1, 64, 0, stream>>>(bsum, rs, nb, N);
  k_scan3<<<nb, 1024, 0, stream>>>(rs, cur, bsum, N);
  k_fill<<<eb, 256, 0, stream>>>(src, dst, cur, csr, E);

  k_prepw<<<256, 256, 0, stream>>>(W0, Wt0);
  k_prepw<<<256, 256, 0, stream>>>(W1, Wt1);

  const dim3 ggrid((N + 127) / 128, 2);
  const int agrid = (N + 3) / 4;

  // layer 0 (fp32 A read directly)
  k_gemm256<true><<<ggrid, 256, 0, stream>>>(x, Wt0, dis, bufU, N);
  k_agg256<<<agrid, 256, 0, stream>>>(bufU, rs, csr, dis, b0, bufH, N);
  // layer 1
  k_gemm256<false><<<ggrid, 256, 0, stream>>>(bufH, Wt1, dis, bufU, N);
  k_agg256<<<agrid, 256, 0, stream>>>(bufU, rs, csr, dis, b1, bufH, N);
  // layer 2
  k_gemm40<<<(N + 63) / 64, 640, 0, stream>>>(bufH, W2, dis, u40, N);
  k_agg40<<<agrid, 256, 0, stream>>>(u40, rs, csr, dis, b2, out, N);
}

// Round 6
// 433.828 us; speedup vs baseline: 1.7807x; 1.0228x over previous
//
#include <hip/hip_runtime.h>
#include <hip/hip_bf16.h>
#include <cstdint>
#include <cstddef>

// GCN 3-layer forward, MI355X (gfx950).
// Round 6: (a) agg256 v3 - uint4/lane, 2 edges per wave via half-waves
// (round-5 showed VALU 40% from per-8B addressing/unpack);
// (b) gemm256 staged via global_load_lds width=16 into unpadded 64B-row LDS
// with seg permutation perm(q,r)=(q+r+(r>>2))&3 to keep ds_read_b128 ~2-way.

typedef unsigned short u16;
typedef unsigned int u32;
typedef __attribute__((ext_vector_type(8))) short bf16x8;
typedef __attribute__((ext_vector_type(4))) float f32x4;

__device__ inline float bfl(u32 u) { return __uint_as_float(u << 16); }
__device__ inline float bfh(u32 u) { return __uint_as_float(u & 0xffff0000u); }
__device__ inline u16 f2bf(float f) {
  __hip_bfloat16 h = __float2bfloat16(f);
  return __builtin_bit_cast(u16, h);
}
__device__ inline u32 pk2bf(float lo, float hi) {
  return ((u32)f2bf(hi) << 16) | (u32)f2bf(lo);
}

// async global->LDS, 16B per lane; LDS dest = base + lane*16 (wave-uniform base)
__device__ inline void gl_lds16(const u16* g, u16* ldsbase) {
  __builtin_amdgcn_global_load_lds(
      (const __attribute__((address_space(1))) u32*)g,
      (__attribute__((address_space(3))) u32*)ldsbase, 16, 0, 0);
}

// ---------------- CSR build ----------------
__global__ void k_count(const int* __restrict__ dst, int* __restrict__ cnt, int E) {
  int e = blockIdx.x * blockDim.x + threadIdx.x;
  if (e < E) atomicAdd(&cnt[dst[e]], 1);
}

__global__ __launch_bounds__(1024) void k_scan1(const int* __restrict__ cnt,
                                                int* __restrict__ rs,
                                                float* __restrict__ dis,
                                                int* __restrict__ bsum, int n) {
  __shared__ int wsum[16];
  const int tid = threadIdx.x;
  const int lane = tid & 63, wid = tid >> 6;
  const int i = blockIdx.x * 1024 + tid;
  const int v = (i < n) ? cnt[i] : 0;
  int x = v;
#pragma unroll
  for (int off = 1; off < 64; off <<= 1) {
    int y = __shfl_up(x, off, 64);
    if (lane >= off) x += y;
  }
  if (lane == 63) wsum[wid] = x;
  __syncthreads();
  if (wid == 0) {
    int w = (lane < 16) ? wsum[lane] : 0;
#pragma unroll
    for (int off = 1; off < 16; off <<= 1) {
      int y = __shfl_up(w, off, 64);
      if (lane >= off) w += y;
    }
    if (lane < 16) wsum[lane] = w;
  }
  __syncthreads();
  const int excl = (wid > 0 ? wsum[wid - 1] : 0) + (x - v);
  if (i < n) {
    rs[i] = excl;
    dis[i] = rsqrtf((float)(1 + v));
  }
  if (tid == 0) bsum[blockIdx.x] = wsum[15];
}

__global__ __launch_bounds__(64) void k_scan2(int* __restrict__ bsum,
                                              int* __restrict__ rs, int nb, int n) {
  const int lane = threadIdx.x;
  int carry = 0;
  for (int base = 0; base < nb; base += 64) {
    const int j = base + lane;
    const int v = (j < nb) ? bsum[j] : 0;
    int x = v;
#pragma unroll
    for (int off = 1; off < 64; off <<= 1) {
      int y = __shfl_up(x, off, 64);
      if (lane >= off) x += y;
    }
    if (j < nb) bsum[j] = carry + (x - v);
    carry += __shfl(x, 63, 64);
  }
  if (lane == 0) rs[n] = carry;
}

__global__ __launch_bounds__(1024) void k_scan3(int* __restrict__ rs,
                                                int* __restrict__ cur,
                                                const int* __restrict__ bsum, int n) {
  const int i = blockIdx.x * 1024 + threadIdx.x;
  if (i < n) {
    const int r = rs[i] + bsum[blockIdx.x];
    rs[i] = r;
    cur[i] = r;
  }
}

__global__ void k_fill(const int* __restrict__ src, const int* __restrict__ dst,
                       int* __restrict__ cur, int* __restrict__ csr, int E) {
  int e = blockIdx.x * blockDim.x + threadIdx.x;
  if (e < E) {
    int p = atomicAdd(&cur[dst[e]], 1);
    csr[p] = src[e];
  }
}

// Wt[n][k] = bf16(W[k][n]), 256x256
__global__ void k_prepw(const float* __restrict__ W, u16* __restrict__ Wt) {
  int t = blockIdx.x * 256 + threadIdx.x;
  int k = t >> 8, n = t & 255;
  Wt[n * 256 + k] = f2bf(W[t]);
}

// ---------------- MFMA GEMM: C[M,256] = A[M,256] @ W, epilogue *dis[m], bf16 out ----------
// 128x128 tile, 4 waves (2x2), wave 64x64 = 4x4 of 16x16x32 MFMA, BK=32.
// LDS: unpadded 64B rows; 16B seg q of row r stored at seg perm(q,r)=(q+r+(r>>2))&3.
// bf16-A path stages via global_load_lds (16B/lane); fp32-A (layer 0) converts in VGPRs.
template <bool F32A>
__global__ __launch_bounds__(256) void k_gemm256(const void* __restrict__ Aptr,
                                                 const u16* __restrict__ Wt,
                                                 const float* __restrict__ dis,
                                                 u16* __restrict__ C, int M) {
  __shared__ u16 As[128 * 32];
  __shared__ u16 Bs[128 * 32];
  const int tid = threadIdx.x;
  const int wid = tid >> 6, lane = tid & 63;
  const int wave_m = wid >> 1, wave_n = wid & 1;
  const int m0 = blockIdx.x * 128, n0 = blockIdx.y * 128;
  const int quad = lane >> 4, col = lane & 15;

  // staging geometry (per lane): covers rows wid*32 .. wid*32+31 in 2 blocks of 16
  const int rl = lane >> 2;          // 0..15 row within block
  const int sseg = lane & 3;         // LDS seg this lane fills

  // fragment LDS offsets (perm invariant across i since 16*i contributes 0 mod 4)
  const int ra = wave_m * 64 + col;
  const int rb = wave_n * 64 + col;
  const int pa = (quad + ra + (ra >> 2)) & 3;
  const int pb = (quad + rb + (rb >> 2)) & 3;

  f32x4 acc[4][4];
#pragma unroll
  for (int i = 0; i < 4; ++i)
#pragma unroll
    for (int j = 0; j < 4; ++j) acc[i][j] = (f32x4){0.f, 0.f, 0.f, 0.f};

  for (int k0 = 0; k0 < 256; k0 += 32) {
#pragma unroll
    for (int blk = 0; blk < 2; ++blk) {
      const int R = wid * 32 + blk * 16;
      const int r = R + rl;
      const int q = (sseg - r - (r >> 2)) & 3;   // global seg to fetch for LDS seg sseg
      if (F32A) {
        // fp32 A: plain load + convert, write through permutation
        const float* A = (const float*)Aptr;
        const int gm = m0 + r;
        float4 lo = make_float4(0.f, 0.f, 0.f, 0.f), hi = lo;
        if (gm < M) {
          lo = *(const float4*)(A + (size_t)gm * 256 + k0 + q * 8);
          hi = *(const float4*)(A + (size_t)gm * 256 + k0 + q * 8 + 4);
        }
        uint4 w;
        w.x = pk2bf(lo.x, lo.y); w.y = pk2bf(lo.z, lo.w);
        w.z = pk2bf(hi.x, hi.y); w.w = pk2bf(hi.z, hi.w);
        *(uint4*)&As[r * 32 + ((q + r + (r >> 2)) & 3) * 8] = w;
      } else {
        const u16* A = (const u16*)Aptr;
        if (m0 + r < M)
          gl_lds16(A + (size_t)(m0 + r) * 256 + k0 + q * 8, &As[R * 32]);
      }
      gl_lds16(Wt + (size_t)(n0 + r) * 256 + k0 + q * 8, &Bs[R * 32]);
    }
    __syncthreads();

    bf16x8 af[4], bf[4];
#pragma unroll
    for (int i = 0; i < 4; ++i)
      af[i] = *(const bf16x8*)&As[(ra + i * 16) * 32 + pa * 8];
#pragma unroll
    for (int j = 0; j < 4; ++j)
      bf[j] = *(const bf16x8*)&Bs[(rb + j * 16) * 32 + pb * 8];
#pragma unroll
    for (int i = 0; i < 4; ++i)
#pragma unroll
      for (int j = 0; j < 4; ++j)
        acc[i][j] = __builtin_amdgcn_mfma_f32_16x16x32_bf16(af[i], bf[j], acc[i][j], 0, 0, 0);
    __syncthreads();
  }

  // epilogue: C/D layout col=lane&15, row=quad*4+t
#pragma unroll
  for (int i = 0; i < 4; ++i) {
    float dd[4];
    int mbase = m0 + wave_m * 64 + i * 16 + quad * 4;
#pragma unroll
    for (int t = 0; t < 4; ++t) dd[t] = (mbase + t < M) ? dis[mbase + t] : 0.f;
#pragma unroll
    for (int j = 0; j < 4; ++j) {
      const int n = n0 + wave_n * 64 + j * 16 + col;
#pragma unroll
      for (int t = 0; t < 4; ++t) {
        const int m = mbase + t;
        if (m < M) C[(size_t)m * 256 + n] = f2bf(acc[i][j][t] * dd[t]);
      }
    }
  }
}

// ---------------- Aggregate 256-dim bf16 v3 ----------------
// wave per dst node; half-wave per edge (2 edges in flight), uint4 (8 dims)/lane.
__global__ __launch_bounds__(256) void k_agg256(const u16* __restrict__ u,
                                                const int* __restrict__ rs,
                                                const int* __restrict__ csr,
                                                const float* __restrict__ dis,
                                                const float* __restrict__ b,
                                                u16* __restrict__ out, int n) {
  const int wid = threadIdx.x >> 6, lane = threadIdx.x & 63;
  const int d = blockIdx.x * 4 + wid;
  if (d >= n) return;
  const int half = lane >> 5, sl = lane & 31;
  const int col = sl << 3;  // 8 bf16 dims per lane
  float a[8];
  {
    const int sidx = half ? n : d;  // self row on half 0; half 1 reads zero row
    const uint4 v = *(const uint4*)(u + (size_t)sidx * 256 + col);
    a[0] = bfl(v.x); a[1] = bfh(v.x); a[2] = bfl(v.y); a[3] = bfh(v.y);
    a[4] = bfl(v.z); a[5] = bfh(v.z); a[6] = bfl(v.w); a[7] = bfh(v.w);
  }
  const int p1 = rs[d + 1];
  for (int p = rs[d]; p < p1; p += 8) {
    int idx[4];
#pragma unroll
    for (int i = 0; i < 4; ++i) {
      const int e = p + 2 * i + half;
      idx[i] = (e < p1) ? csr[e] : n;  // row n = zeros
    }
    uint4 v[4];
#pragma unroll
    for (int i = 0; i < 4; ++i)
      v[i] = *(const uint4*)(u + (size_t)idx[i] * 256 + col);
#pragma unroll
    for (int i = 0; i < 4; ++i) {
      a[0] += bfl(v[i].x); a[1] += bfh(v[i].x);
      a[2] += bfl(v[i].y); a[3] += bfh(v[i].y);
      a[4] += bfl(v[i].z); a[5] += bfh(v[i].z);
      a[6] += bfl(v[i].w); a[7] += bfh(v[i].w);
    }
  }
#pragma unroll
  for (int j = 0; j < 8; ++j) a[j] += __shfl_xor(a[j], 32, 64);
  if (half == 0) {
    const float dd = dis[d];
    const float4 b0 = *(const float4*)(b + col);
    const float4 b1 = *(const float4*)(b + col + 4);
    uint4 o;
    o.x = pk2bf(fmaxf(dd * a[0] + b0.x, 0.f), fmaxf(dd * a[1] + b0.y, 0.f));
    o.y = pk2bf(fmaxf(dd * a[2] + b0.z, 0.f), fmaxf(dd * a[3] + b0.w, 0.f));
    o.z = pk2bf(fmaxf(dd * a[4] + b1.x, 0.f), fmaxf(dd * a[5] + b1.y, 0.f));
    o.w = pk2bf(fmaxf(dd * a[6] + b1.z, 0.f), fmaxf(dd * a[7] + b1.w, 0.f));
    *(uint4*)(out + (size_t)d * 256 + col) = o;
  }
}

// ---------------- GEMM: C[M,40] = A_bf16[M,256] @ W2_f32[256,40], *dis[m] ----------------
__global__ __launch_bounds__(640) void k_gemm40(const u16* __restrict__ A,
                                                const float* __restrict__ W,
                                                const float* __restrict__ dis,
                                                float* __restrict__ C, int M) {
  __shared__ float Ws[256 * 40];
  for (int i = threadIdx.x; i < 256 * 40 / 4; i += 640)
    ((float4*)Ws)[i] = ((const float4*)W)[i];
  __syncthreads();
  const int ng = threadIdx.x % 10;
  const int ml = threadIdx.x / 10;
  const int m = blockIdx.x * 64 + ml;
  if (m >= M) return;
  const u16* __restrict__ arow = A + (size_t)m * 256;
  float4 acc = make_float4(0.f, 0.f, 0.f, 0.f);
  const int nc = ng << 2;
#pragma unroll 2
  for (int k = 0; k < 256; k += 8) {
    const uint4 av = *(const uint4*)(arow + k);
    float a[8] = {bfl(av.x), bfh(av.x), bfl(av.y), bfh(av.y),
                  bfl(av.z), bfh(av.z), bfl(av.w), bfh(av.w)};
#pragma unroll
    for (int kk = 0; kk < 8; ++kk) {
      const float4 w = *(const float4*)&Ws[(k + kk) * 40 + nc];
      acc.x += a[kk] * w.x; acc.y += a[kk] * w.y;
      acc.z += a[kk] * w.z; acc.w += a[kk] * w.w;
    }
  }
  const float dd = dis[m];
  *(float4*)(C + (size_t)m * 40 + nc) =
      make_float4(acc.x * dd, acc.y * dd, acc.z * dd, acc.w * dd);
}

// ---------------- Aggregate 40-dim + bias + log_softmax, 8-way unrolled ----------------
__global__ __launch_bounds__(256) void k_agg40(const float* __restrict__ u,
                                               const int* __restrict__ rs,
                                               const int* __restrict__ csr,
                                               const float* __restrict__ dis,
                                               const float* __restrict__ b,
                                               float* __restrict__ out, int n) {
  const int wid = threadIdx.x >> 6, lane = threadIdx.x & 63;
  const int d = blockIdx.x * 4 + wid;
  if (d >= n) return;
  const bool act = lane < 40;
  const int cl = act ? lane : 0;
  float acc = act ? u[(size_t)d * 40 + lane] : 0.f;
  const int p1 = rs[d + 1];
  for (int p = rs[d]; p < p1; p += 8) {
    int idx[8];
#pragma unroll
    for (int i = 0; i < 8; ++i) idx[i] = (p + i < p1) ? csr[p + i] : n;  // row n = zeros
    float v[8];
#pragma unroll
    for (int i = 0; i < 8; ++i) v[i] = u[(size_t)idx[i] * 40 + cl];
    float s = 0.f;
#pragma unroll
    for (int i = 0; i < 8; ++i) s += v[i];
    if (act) acc += s;
  }
  const float logit = act ? dis[d] * acc + b[lane] : -INFINITY;
  float mx = logit;
#pragma unroll
  for (int off = 32; off; off >>= 1) mx = fmaxf(mx, __shfl_xor(mx, off, 64));
  float ex = act ? expf(logit - mx) : 0.f;
  float sm = ex;
#pragma unroll
  for (int off = 32; off; off >>= 1) sm += __shfl_xor(sm, off, 64);
  if (act) out[(size_t)d * 40 + lane] = logit - mx - logf(sm);
}

// ---------------- launch ----------------
extern "C" void kernel_launch(void* const* d_in, const int* in_sizes, int n_in,
                              void* d_out, int out_size, void* d_ws, size_t ws_size,
                              hipStream_t stream) {
  const float* x  = (const float*)d_in[0];
  const int*   ei = (const int*)d_in[1];
  const float* W0 = (const float*)d_in[2];
  const float* b0 = (const float*)d_in[3];
  const float* W1 = (const float*)d_in[4];
  const float* b1 = (const float*)d_in[5];
  const float* W2 = (const float*)d_in[6];
  const float* b2 = (const float*)d_in[7];
  float* out = (float*)d_out;

  const int N = in_sizes[0] / 256;
  const int E = in_sizes[1] / 2;
  const int* src = ei;
  const int* dst = ei + E;

  char* p = (char*)d_ws;
  auto carve = [&](size_t bytes) {
    char* q = p;
    p += (bytes + 255) & ~(size_t)255;
    return q;
  };
  u16*   bufU = (u16*)carve((size_t)(N + 1) * 256 * 2);  // +1 zero row for tail pad
  u16*   bufH = (u16*)carve((size_t)(N + 1) * 256 * 2);
  float* u40  = (float*)carve((size_t)(N + 1) * 40 * 4);
  u16*   Wt0  = (u16*)carve(256 * 256 * 2);
  u16*   Wt1  = (u16*)carve(256 * 256 * 2);
  float* dis  = (float*)carve((size_t)N * 4);
  int*   cnt  = (int*)carve((size_t)N * 4);
  int*   rs   = (int*)carve((size_t)(N + 1) * 4);
  int*   cur  = (int*)carve((size_t)N * 4);
  int*   csr  = (int*)carve((size_t)(E + 8) * 4);
  int*   bsum = (int*)carve(1024 * 4);

  // zero rows for gather tail padding + cnt init
  hipMemsetAsync(cnt, 0, (size_t)N * 4, stream);
  hipMemsetAsync(bufU + (size_t)N * 256, 0, 512, stream);
  hipMemsetAsync(bufH + (size_t)N * 256, 0, 512, stream);
  hipMemsetAsync(u40 + (size_t)N * 40, 0, 160, stream);

  // CSR + deg: count -> 3-phase hierarchical scan -> fill
  const int eb = (E + 255) / 256;
  const int nb = (N + 1023) / 1024;
  k_count<<<eb, 256, 0, stream>>>(dst, cnt, E);
  k_scan1<<<nb, 1024, 0, stream>>>(cnt, rs, dis, bsum, N);
  k_scan2<<<1, 64, 0, stream>>>(bsum, rs, nb, N);
  k_scan3<<<nb, 1024, 0, stream>>>(rs, cur, bsum, N);
  k_fill<<<eb, 256, 0, stream>>>(src, dst, cur, csr, E);

  k_prepw<<<256, 256, 0, stream>>>(W0, Wt0);
  k_prepw<<<256, 256, 0, stream>>>(W1, Wt1);

  const dim3 ggrid((N + 127) / 128, 2);
  const int agrid = (N + 3) / 4;

  // layer 0 (fp32 A read directly)
  k_gemm256<true><<<ggrid, 256, 0, stream>>>(x, Wt0, dis, bufU, N);
  k_agg256<<<agrid, 256, 0, stream>>>(bufU, rs, csr, dis, b0, bufH, N);
  // layer 1
  k_gemm256<false><<<ggrid, 256, 0, stream>>>(bufH, Wt1, dis, bufU, N);
  k_agg256<<<agrid, 256, 0, stream>>>(bufU, rs, csr, dis, b1, bufH, N);
  // layer 2
  k_gemm40<<<(N + 63) / 64, 640, 0, stream>>>(bufH, W2, dis, u40, N);
  k_agg40<<<agrid, 256, 0, stream>>>(u40, rs, csr, dis, b2, out, N);
}

// Round 7
// 412.550 us; speedup vs baseline: 1.8725x; 1.0516x over previous
//
#include <hip/hip_runtime.h>
#include <hip/hip_bf16.h>
#include <cstdint>
#include <cstddef>

// GCN 3-layer forward, MI355X (gfx950).
// Round 7: agg40 v2 (20-lane float2 slots, 12 edges in flight), gemm40 via
// MFMA with global-resident bf16 W2^T, fused prep kernel (21 -> 12 dispatches).
// agg256 pinned at ~7.5 TB/s random-gather L2 ceiling (rounds 4-6 evidence);
// left unchanged.

typedef unsigned short u16;
typedef unsigned int u32;
typedef __attribute__((ext_vector_type(8))) short bf16x8;
typedef __attribute__((ext_vector_type(4))) float f32x4;

__device__ inline float bfl(u32 u) { return __uint_as_float(u << 16); }
__device__ inline float bfh(u32 u) { return __uint_as_float(u & 0xffff0000u); }
__device__ inline u16 f2bf(float f) {
  __hip_bfloat16 h = __float2bfloat16(f);
  return __builtin_bit_cast(u16, h);
}
__device__ inline u32 pk2bf(float lo, float hi) {
  return ((u32)f2bf(hi) << 16) | (u32)f2bf(lo);
}

// async global->LDS, 16B per lane; LDS dest = base + lane*16 (wave-uniform base)
__device__ inline void gl_lds16(const u16* g, u16* ldsbase) {
  __builtin_amdgcn_global_load_lds(
      (const __attribute__((address_space(1))) u32*)g,
      (__attribute__((address_space(3))) u32*)ldsbase, 16, 0, 0);
}

// ---------------- fused prep: W transposes + cnt zero + zero rows ----------------
__global__ void k_prep(const float* __restrict__ W0, const float* __restrict__ W1,
                       const float* __restrict__ W2,
                       u16* __restrict__ Wt0, u16* __restrict__ Wt1,
                       u16* __restrict__ Wt2, int* __restrict__ cnt,
                       u16* __restrict__ z256a, u16* __restrict__ z256b,
                       float* __restrict__ z40, int n) {
  const int t = blockIdx.x * 256 + threadIdx.x;
  if (t < 65536) {                       // Wt0/Wt1: [n][k] = bf16(W[k][n])
    const int k = t >> 8, c = t & 255;
    Wt0[c * 256 + k] = f2bf(W0[t]);
    Wt1[c * 256 + k] = f2bf(W1[t]);
  } else if (t < 65536 + 16384) {        // Wt2: 64x256, cols 40..63 zero
    const int t2 = t - 65536;
    const int k = t2 >> 6, nn = t2 & 63;
    const float v = (nn < 40) ? W2[k * 40 + nn] : 0.f;
    Wt2[nn * 256 + k] = f2bf(v);
  }
  const int u = t - (65536 + 16384);
  if (u >= 0) {
    if (u < n) cnt[u] = 0;
    if (u < 256) { z256a[u] = 0; z256b[u] = 0; }
    if (u < 40) z40[u] = 0.f;
  }
}

// ---------------- CSR build ----------------
__global__ void k_count(const int* __restrict__ dst, int* __restrict__ cnt, int E) {
  int e = blockIdx.x * blockDim.x + threadIdx.x;
  if (e < E) atomicAdd(&cnt[dst[e]], 1);
}

__global__ __launch_bounds__(1024) void k_scan1(const int* __restrict__ cnt,
                                                int* __restrict__ rs,
                                                float* __restrict__ dis,
                                                int* __restrict__ bsum, int n) {
  __shared__ int wsum[16];
  const int tid = threadIdx.x;
  const int lane = tid & 63, wid = tid >> 6;
  const int i = blockIdx.x * 1024 + tid;
  const int v = (i < n) ? cnt[i] : 0;
  int x = v;
#pragma unroll
  for (int off = 1; off < 64; off <<= 1) {
    int y = __shfl_up(x, off, 64);
    if (lane >= off) x += y;
  }
  if (lane == 63) wsum[wid] = x;
  __syncthreads();
  if (wid == 0) {
    int w = (lane < 16) ? wsum[lane] : 0;
#pragma unroll
    for (int off = 1; off < 16; off <<= 1) {
      int y = __shfl_up(w, off, 64);
      if (lane >= off) w += y;
    }
    if (lane < 16) wsum[lane] = w;
  }
  __syncthreads();
  const int excl = (wid > 0 ? wsum[wid - 1] : 0) + (x - v);
  if (i < n) {
    rs[i] = excl;
    dis[i] = rsqrtf((float)(1 + v));
  }
  if (tid == 0) bsum[blockIdx.x] = wsum[15];
}

__global__ __launch_bounds__(64) void k_scan2(int* __restrict__ bsum,
                                              int* __restrict__ rs, int nb, int n) {
  const int lane = threadIdx.x;
  int carry = 0;
  for (int base = 0; base < nb; base += 64) {
    const int j = base + lane;
    const int v = (j < nb) ? bsum[j] : 0;
    int x = v;
#pragma unroll
    for (int off = 1; off < 64; off <<= 1) {
      int y = __shfl_up(x, off, 64);
      if (lane >= off) x += y;
    }
    if (j < nb) bsum[j] = carry + (x - v);
    carry += __shfl(x, 63, 64);
  }
  if (lane == 0) rs[n] = carry;
}

__global__ __launch_bounds__(1024) void k_scan3(int* __restrict__ rs,
                                                int* __restrict__ cur,
                                                const int* __restrict__ bsum, int n) {
  const int i = blockIdx.x * 1024 + threadIdx.x;
  if (i < n) {
    const int r = rs[i] + bsum[blockIdx.x];
    rs[i] = r;
    cur[i] = r;
  }
}

__global__ void k_fill(const int* __restrict__ src, const int* __restrict__ dst,
                       int* __restrict__ cur, int* __restrict__ csr, int E) {
  int e = blockIdx.x * blockDim.x + threadIdx.x;
  if (e < E) {
    int p = atomicAdd(&cur[dst[e]], 1);
    csr[p] = src[e];
  }
}

// ---------------- MFMA GEMM: C[M,256] = A[M,256] @ W, epilogue *dis[m], bf16 out ----------
// 128x128 tile, 4 waves (2x2), wave 64x64 = 4x4 of 16x16x32 MFMA, BK=32.
// LDS: unpadded 64B rows; 16B seg q of row r stored at seg perm(q,r)=(q+r+(r>>2))&3.
template <bool F32A>
__global__ __launch_bounds__(256) void k_gemm256(const void* __restrict__ Aptr,
                                                 const u16* __restrict__ Wt,
                                                 const float* __restrict__ dis,
                                                 u16* __restrict__ C, int M) {
  __shared__ u16 As[128 * 32];
  __shared__ u16 Bs[128 * 32];
  const int tid = threadIdx.x;
  const int wid = tid >> 6, lane = tid & 63;
  const int wave_m = wid >> 1, wave_n = wid & 1;
  const int m0 = blockIdx.x * 128, n0 = blockIdx.y * 128;
  const int quad = lane >> 4, col = lane & 15;

  const int rl = lane >> 2;          // 0..15 row within 16-row staging block
  const int sseg = lane & 3;         // LDS seg this lane fills

  const int ra = wave_m * 64 + col;
  const int rb = wave_n * 64 + col;
  const int pa = (quad + ra + (ra >> 2)) & 3;
  const int pb = (quad + rb + (rb >> 2)) & 3;

  f32x4 acc[4][4];
#pragma unroll
  for (int i = 0; i < 4; ++i)
#pragma unroll
    for (int j = 0; j < 4; ++j) acc[i][j] = (f32x4){0.f, 0.f, 0.f, 0.f};

  for (int k0 = 0; k0 < 256; k0 += 32) {
#pragma unroll
    for (int blk = 0; blk < 2; ++blk) {
      const int R = wid * 32 + blk * 16;
      const int r = R + rl;
      const int q = (sseg - r - (r >> 2)) & 3;
      if (F32A) {
        const float* A = (const float*)Aptr;
        const int gm = m0 + r;
        float4 lo = make_float4(0.f, 0.f, 0.f, 0.f), hi = lo;
        if (gm < M) {
          lo = *(const float4*)(A + (size_t)gm * 256 + k0 + q * 8);
          hi = *(const float4*)(A + (size_t)gm * 256 + k0 + q * 8 + 4);
        }
        uint4 w;
        w.x = pk2bf(lo.x, lo.y); w.y = pk2bf(lo.z, lo.w);
        w.z = pk2bf(hi.x, hi.y); w.w = pk2bf(hi.z, hi.w);
        *(uint4*)&As[r * 32 + ((q + r + (r >> 2)) & 3) * 8] = w;
      } else {
        const u16* A = (const u16*)Aptr;
        if (m0 + r < M)
          gl_lds16(A + (size_t)(m0 + r) * 256 + k0 + q * 8, &As[R * 32]);
      }
      gl_lds16(Wt + (size_t)(n0 + r) * 256 + k0 + q * 8, &Bs[R * 32]);
    }
    __syncthreads();

    bf16x8 af[4], bf[4];
#pragma unroll
    for (int i = 0; i < 4; ++i)
      af[i] = *(const bf16x8*)&As[(ra + i * 16) * 32 + pa * 8];
#pragma unroll
    for (int j = 0; j < 4; ++j)
      bf[j] = *(const bf16x8*)&Bs[(rb + j * 16) * 32 + pb * 8];
#pragma unroll
    for (int i = 0; i < 4; ++i)
#pragma unroll
      for (int j = 0; j < 4; ++j)
        acc[i][j] = __builtin_amdgcn_mfma_f32_16x16x32_bf16(af[i], bf[j], acc[i][j], 0, 0, 0);
    __syncthreads();
  }

#pragma unroll
  for (int i = 0; i < 4; ++i) {
    float dd[4];
    int mbase = m0 + wave_m * 64 + i * 16 + quad * 4;
#pragma unroll
    for (int t = 0; t < 4; ++t) dd[t] = (mbase + t < M) ? dis[mbase + t] : 0.f;
#pragma unroll
    for (int j = 0; j < 4; ++j) {
      const int n = n0 + wave_n * 64 + j * 16 + col;
#pragma unroll
      for (int t = 0; t < 4; ++t) {
        const int m = mbase + t;
        if (m < M) C[(size_t)m * 256 + n] = f2bf(acc[i][j][t] * dd[t]);
      }
    }
  }
}

// ---------------- Aggregate 256-dim bf16 v3 (unchanged) ----------------
__global__ __launch_bounds__(256) void k_agg256(const u16* __restrict__ u,
                                                const int* __restrict__ rs,
                                                const int* __restrict__ csr,
                                                const float* __restrict__ dis,
                                                const float* __restrict__ b,
                                                u16* __restrict__ out, int n) {
  const int wid = threadIdx.x >> 6, lane = threadIdx.x & 63;
  const int d = blockIdx.x * 4 + wid;
  if (d >= n) return;
  const int half = lane >> 5, sl = lane & 31;
  const int col = sl << 3;
  float a[8];
  {
    const int sidx = half ? n : d;
    const uint4 v = *(const uint4*)(u + (size_t)sidx * 256 + col);
    a[0] = bfl(v.x); a[1] = bfh(v.x); a[2] = bfl(v.y); a[3] = bfh(v.y);
    a[4] = bfl(v.z); a[5] = bfh(v.z); a[6] = bfl(v.w); a[7] = bfh(v.w);
  }
  const int p1 = rs[d + 1];
  for (int p = rs[d]; p < p1; p += 8) {
    int idx[4];
#pragma unroll
    for (int i = 0; i < 4; ++i) {
      const int e = p + 2 * i + half;
      idx[i] = (e < p1) ? csr[e] : n;
    }
    uint4 v[4];
#pragma unroll
    for (int i = 0; i < 4; ++i)
      v[i] = *(const uint4*)(u + (size_t)idx[i] * 256 + col);
#pragma unroll
    for (int i = 0; i < 4; ++i) {
      a[0] += bfl(v[i].x); a[1] += bfh(v[i].x);
      a[2] += bfl(v[i].y); a[3] += bfh(v[i].y);
      a[4] += bfl(v[i].z); a[5] += bfh(v[i].z);
      a[6] += bfl(v[i].w); a[7] += bfh(v[i].w);
    }
  }
#pragma unroll
  for (int j = 0; j < 8; ++j) a[j] += __shfl_xor(a[j], 32, 64);
  if (half == 0) {
    const float dd = dis[d];
    const float4 b0 = *(const float4*)(b + col);
    const float4 b1 = *(const float4*)(b + col + 4);
    uint4 o;
    o.x = pk2bf(fmaxf(dd * a[0] + b0.x, 0.f), fmaxf(dd * a[1] + b0.y, 0.f));
    o.y = pk2bf(fmaxf(dd * a[2] + b0.z, 0.f), fmaxf(dd * a[3] + b0.w, 0.f));
    o.z = pk2bf(fmaxf(dd * a[4] + b1.x, 0.f), fmaxf(dd * a[5] + b1.y, 0.f));
    o.w = pk2bf(fmaxf(dd * a[6] + b1.z, 0.f), fmaxf(dd * a[7] + b1.w, 0.f));
    *(uint4*)(out + (size_t)d * 256 + col) = o;
  }
}

// ---------------- MFMA GEMM: u40[M,40] = A_bf16[M,256] @ W2, *dis[m], fp32 out -------
// Wt2: [64][256] bf16 in global (L1/L2-resident, 32KB). Wave: 32 rows x 48 cols
// (2x3 tiles of 16x16x32); block = 4 waves = 128 rows. No LDS, no K-loop syncs.
__global__ __launch_bounds__(256) void k_gemm40(const u16* __restrict__ A,
                                                const u16* __restrict__ Wt2,
                                                const float* __restrict__ dis,
                                                float* __restrict__ C, int M) {
  const int wv = threadIdx.x >> 6, lane = threadIdx.x & 63;
  const int quad = lane >> 4, col = lane & 15;
  const int m0 = blockIdx.x * 128 + wv * 32;
  f32x4 acc[2][3];
#pragma unroll
  for (int i = 0; i < 2; ++i)
#pragma unroll
    for (int j = 0; j < 3; ++j) acc[i][j] = (f32x4){0.f, 0.f, 0.f, 0.f};
  for (int k0 = 0; k0 < 256; k0 += 32) {
    bf16x8 af[2], bf[3];
#pragma unroll
    for (int i = 0; i < 2; ++i) {
      int row = m0 + i * 16 + col;
      row = (row < M) ? row : (M - 1);   // clamp; garbage rows never stored
      af[i] = *(const bf16x8*)(A + (size_t)row * 256 + k0 + quad * 8);
    }
#pragma unroll
    for (int j = 0; j < 3; ++j)
      bf[j] = *(const bf16x8*)(Wt2 + (size_t)(j * 16 + col) * 256 + k0 + quad * 8);
#pragma unroll
    for (int i = 0; i < 2; ++i)
#pragma unroll
      for (int j = 0; j < 3; ++j)
        acc[i][j] = __builtin_amdgcn_mfma_f32_16x16x32_bf16(af[i], bf[j], acc[i][j], 0, 0, 0);
  }
#pragma unroll
  for (int i = 0; i < 2; ++i) {
    const int mb = m0 + i * 16 + quad * 4;
#pragma unroll
    for (int j = 0; j < 3; ++j) {
      const int nn = j * 16 + col;
      if (nn < 40) {
#pragma unroll
        for (int t = 0; t < 4; ++t) {
          const int m = mb + t;
          if (m < M) C[(size_t)m * 40 + nn] = acc[i][j][t] * dis[m];
        }
      }
    }
  }
}

// ---------------- Aggregate 40-dim + bias + log_softmax v2 ----------------
// wave per dst; 3 edge-slots of 20 lanes (float2 = 2 dims/lane), x4 unroll.
__global__ __launch_bounds__(256) void k_agg40(const float* __restrict__ u,
                                               const int* __restrict__ rs,
                                               const int* __restrict__ csr,
                                               const float* __restrict__ dis,
                                               const float* __restrict__ b,
                                               float* __restrict__ out, int n) {
  const int wid = threadIdx.x >> 6, lane = threadIdx.x & 63;
  const int d = blockIdx.x * 4 + wid;
  if (d >= n) return;
  const int slot = lane / 20;        // 0,1,2 active; 3 = lanes 60-63 idle
  const int sl = lane % 20;
  const bool act = slot < 3;
  const int col = sl * 2;
  float a0 = 0.f, a1 = 0.f;
  if (slot == 0) {                   // self-loop term
    const float2 v = *(const float2*)(u + (size_t)d * 40 + col);
    a0 = v.x; a1 = v.y;
  }
  const int p1 = rs[d + 1];
  for (int p = rs[d]; p < p1; p += 12) {
    int idx[4];
#pragma unroll
    for (int i = 0; i < 4; ++i) {
      const int e = p + 3 * i + slot;
      idx[i] = (act && e < p1) ? csr[e] : n;  // row n = zeros
    }
    float2 v[4];
#pragma unroll
    for (int i = 0; i < 4; ++i)
      v[i] = *(const float2*)(u + (size_t)idx[i] * 40 + col);
#pragma unroll
    for (int i = 0; i < 4; ++i) { a0 += v[i].x; a1 += v[i].y; }
  }
  // combine slots into lanes 0..19
  a0 += __shfl(a0, lane + 20, 64) + __shfl(a0, lane + 40, 64);
  a1 += __shfl(a1, lane + 20, 64) + __shfl(a1, lane + 40, 64);
  float l0 = -INFINITY, l1 = -INFINITY;
  if (lane < 20) {
    const float dd = dis[d];
    l0 = dd * a0 + b[col];
    l1 = dd * a1 + b[col + 1];
  }
  float mx = fmaxf(l0, l1);
#pragma unroll
  for (int off = 16; off; off >>= 1) mx = fmaxf(mx, __shfl_xor(mx, off, 32));
  float e0 = (lane < 20) ? expf(l0 - mx) : 0.f;
  float e1 = (lane < 20) ? expf(l1 - mx) : 0.f;
  float sm = e0 + e1;
#pragma unroll
  for (int off = 16; off; off >>= 1) sm += __shfl_xor(sm, off, 32);
  if (lane < 20) {
    const float ls = mx + logf(sm);
    float2 o = make_float2(l0 - ls, l1 - ls);
    *(float2*)(out + (size_t)d * 40 + col) = o;
  }
}

// ---------------- launch ----------------
extern "C" void kernel_launch(void* const* d_in, const int* in_sizes, int n_in,
                              void* d_out, int out_size, void* d_ws, size_t ws_size,
                              hipStream_t stream) {
  const float* x  = (const float*)d_in[0];
  const int*   ei = (const int*)d_in[1];
  const float* W0 = (const float*)d_in[2];
  const float* b0 = (const float*)d_in[3];
  const float* W1 = (const float*)d_in[4];
  const float* b1 = (const float*)d_in[5];
  const float* W2 = (const float*)d_in[6];
  const float* b2 = (const float*)d_in[7];
  float* out = (float*)d_out;

  const int N = in_sizes[0] / 256;
  const int E = in_sizes[1] / 2;
  const int* src = ei;
  const int* dst = ei + E;

  char* p = (char*)d_ws;
  auto carve = [&](size_t bytes) {
    char* q = p;
    p += (bytes + 255) & ~(size_t)255;
    return q;
  };
  u16*   bufU = (u16*)carve((size_t)(N + 1) * 256 * 2);  // +1 zero row
  u16*   bufH = (u16*)carve((size_t)(N + 1) * 256 * 2);
  float* u40  = (float*)carve((size_t)(N + 1) * 40 * 4);
  u16*   Wt0  = (u16*)carve(256 * 256 * 2);
  u16*   Wt1  = (u16*)carve(256 * 256 * 2);
  u16*   Wt2  = (u16*)carve(64 * 256 * 2);
  float* dis  = (float*)carve((size_t)N * 4);
  int*   cnt  = (int*)carve((size_t)N * 4);
  int*   rs   = (int*)carve((size_t)(N + 1) * 4);
  int*   cur  = (int*)carve((size_t)N * 4);
  int*   csr  = (int*)carve((size_t)(E + 16) * 4);
  int*   bsum = (int*)carve(1024 * 4);

  // fused prep (replaces 2x prepw + 4 memsets)
  const int prep_items = 65536 + 16384 + N;
  k_prep<<<(prep_items + 255) / 256, 256, 0, stream>>>(
      W0, W1, W2, Wt0, Wt1, Wt2, cnt,
      bufU + (size_t)N * 256, bufH + (size_t)N * 256, u40 + (size_t)N * 40, N);

  // CSR + deg
  const int eb = (E + 255) / 256;
  const int nb = (N + 1023) / 1024;
  k_count<<<eb, 256, 0, stream>>>(dst, cnt, E);
  k_scan1<<<nb, 1024, 0, stream>>>(cnt, rs, dis, bsum, N);
  k_scan2<<<1, 64, 0, stream>>>(bsum, rs, nb, N);
  k_scan3<<<nb, 1024, 0, stream>>>(rs, cur, bsum, N);
  k_fill<<<eb, 256, 0, stream>>>(src, dst, cur, csr, E);

  const dim3 ggrid((N + 127) / 128, 2);
  const int agrid = (N + 3) / 4;

  // layer 0 (fp32 A read directly)
  k_gemm256<true><<<ggrid, 256, 0, stream>>>(x, Wt0, dis, bufU, N);
  k_agg256<<<agrid, 256, 0, stream>>>(bufU, rs, csr, dis, b0, bufH, N);
  // layer 1
  k_gemm256<false><<<ggrid, 256, 0, stream>>>(bufH, Wt1, dis, bufU, N);
  k_agg256<<<agrid, 256, 0, stream>>>(bufU, rs, csr, dis, b1, bufH, N);
  // layer 2
  k_gemm40<<<(N + 127) / 128, 256, 0, stream>>>(bufH, Wt2, dis, u40, N);
  k_agg40<<<agrid, 256, 0, stream>>>(u40, rs, csr, dis, b2, out, N);
}

// Round 8
// 386.373 us; speedup vs baseline: 1.9994x; 1.0678x over previous
//
#include <hip/hip_runtime.h>
#include <hip/hip_bf16.h>
#include <cstdint>
#include <cstddef>

// GCN 3-layer forward, MI355X (gfx950).
// Round 8: gemm256 v3 - BK=64 (32 MFMA/barrier-pair), swapped-operand MFMA so
// C-fragment is m=lane, 4-consecutive-n per reg -> packed uint2 stores (was 64
// scattered 2B stores/lane). gemm40 gets the same operand swap + float4 store.
// agg256 left at its L2-miss-path floor (186MB @ ~3.2TB/s = 58us, r4-7 data).

typedef unsigned short u16;
typedef unsigned int u32;
typedef __attribute__((ext_vector_type(8))) short bf16x8;
typedef __attribute__((ext_vector_type(4))) float f32x4;

__device__ inline float bfl(u32 u) { return __uint_as_float(u << 16); }
__device__ inline float bfh(u32 u) { return __uint_as_float(u & 0xffff0000u); }
__device__ inline u16 f2bf(float f) {
  __hip_bfloat16 h = __float2bfloat16(f);
  return __builtin_bit_cast(u16, h);
}
__device__ inline u32 pk2bf(float lo, float hi) {
  return ((u32)f2bf(hi) << 16) | (u32)f2bf(lo);
}

// async global->LDS, 16B per lane; LDS dest = base + lane*16 (wave-uniform base)
__device__ inline void gl_lds16(const u16* g, u16* ldsbase) {
  __builtin_amdgcn_global_load_lds(
      (const __attribute__((address_space(1))) u32*)g,
      (__attribute__((address_space(3))) u32*)ldsbase, 16, 0, 0);
}

// ---------------- fused prep: W transposes + cnt zero + zero rows ----------------
__global__ void k_prep(const float* __restrict__ W0, const float* __restrict__ W1,
                       const float* __restrict__ W2,
                       u16* __restrict__ Wt0, u16* __restrict__ Wt1,
                       u16* __restrict__ Wt2, int* __restrict__ cnt,
                       u16* __restrict__ z256a, u16* __restrict__ z256b,
                       float* __restrict__ z40, int n) {
  const int t = blockIdx.x * 256 + threadIdx.x;
  if (t < 65536) {                       // Wt0/Wt1: [n][k] = bf16(W[k][n])
    const int k = t >> 8, c = t & 255;
    Wt0[c * 256 + k] = f2bf(W0[t]);
    Wt1[c * 256 + k] = f2bf(W1[t]);
  } else if (t < 65536 + 16384) {        // Wt2: 64x256, cols 40..63 zero
    const int t2 = t - 65536;
    const int k = t2 >> 6, nn = t2 & 63;
    const float v = (nn < 40) ? W2[k * 40 + nn] : 0.f;
    Wt2[nn * 256 + k] = f2bf(v);
  }
  const int u = t - (65536 + 16384);
  if (u >= 0) {
    if (u < n) cnt[u] = 0;
    if (u < 256) { z256a[u] = 0; z256b[u] = 0; }
    if (u < 40) z40[u] = 0.f;
  }
}

// ---------------- CSR build ----------------
__global__ void k_count(const int* __restrict__ dst, int* __restrict__ cnt, int E) {
  int e = blockIdx.x * blockDim.x + threadIdx.x;
  if (e < E) atomicAdd(&cnt[dst[e]], 1);
}

__global__ __launch_bounds__(1024) void k_scan1(const int* __restrict__ cnt,
                                                int* __restrict__ rs,
                                                float* __restrict__ dis,
                                                int* __restrict__ bsum, int n) {
  __shared__ int wsum[16];
  const int tid = threadIdx.x;
  const int lane = tid & 63, wid = tid >> 6;
  const int i = blockIdx.x * 1024 + tid;
  const int v = (i < n) ? cnt[i] : 0;
  int x = v;
#pragma unroll
  for (int off = 1; off < 64; off <<= 1) {
    int y = __shfl_up(x, off, 64);
    if (lane >= off) x += y;
  }
  if (lane == 63) wsum[wid] = x;
  __syncthreads();
  if (wid == 0) {
    int w = (lane < 16) ? wsum[lane] : 0;
#pragma unroll
    for (int off = 1; off < 16; off <<= 1) {
      int y = __shfl_up(w, off, 64);
      if (lane >= off) w += y;
    }
    if (lane < 16) wsum[lane] = w;
  }
  __syncthreads();
  const int excl = (wid > 0 ? wsum[wid - 1] : 0) + (x - v);
  if (i < n) {
    rs[i] = excl;
    dis[i] = rsqrtf((float)(1 + v));
  }
  if (tid == 0) bsum[blockIdx.x] = wsum[15];
}

__global__ __launch_bounds__(64) void k_scan2(int* __restrict__ bsum,
                                              int* __restrict__ rs, int nb, int n) {
  const int lane = threadIdx.x;
  int carry = 0;
  for (int base = 0; base < nb; base += 64) {
    const int j = base + lane;
    const int v = (j < nb) ? bsum[j] : 0;
    int x = v;
#pragma unroll
    for (int off = 1; off < 64; off <<= 1) {
      int y = __shfl_up(x, off, 64);
      if (lane >= off) x += y;
    }
    if (j < nb) bsum[j] = carry + (x - v);
    carry += __shfl(x, 63, 64);
  }
  if (lane == 0) rs[n] = carry;
}

__global__ __launch_bounds__(1024) void k_scan3(int* __restrict__ rs,
                                                int* __restrict__ cur,
                                                const int* __restrict__ bsum, int n) {
  const int i = blockIdx.x * 1024 + threadIdx.x;
  if (i < n) {
    const int r = rs[i] + bsum[blockIdx.x];
    rs[i] = r;
    cur[i] = r;
  }
}

__global__ void k_fill(const int* __restrict__ src, const int* __restrict__ dst,
                       int* __restrict__ cur, int* __restrict__ csr, int E) {
  int e = blockIdx.x * blockDim.x + threadIdx.x;
  if (e < E) {
    int p = atomicAdd(&cur[dst[e]], 1);
    csr[p] = src[e];
  }
}

// ---------------- MFMA GEMM: C[M,256] = A[M,256] @ W, epilogue *dis[m], bf16 out ----------
// 128x128 tile, 4 waves (2x2), wave 64x64 = 4x4 of 16x16x32, BK=64 (2 k-steps/iter,
// 32 MFMA per barrier pair). LDS: 128B rows, 16B seg q of row r at slot (q+r)&7
// (balanced b128 reads: 8 lanes per 4-bank group = 32B/bank). Swapped-operand MFMA:
// mfma(bf, af) -> lane&15 = m, reg group = 4 consecutive n -> uint2 packed stores.
template <bool F32A>
__global__ __launch_bounds__(256) void k_gemm256(const void* __restrict__ Aptr,
                                                 const u16* __restrict__ Wt,
                                                 const float* __restrict__ dis,
                                                 u16* __restrict__ C, int M) {
  __shared__ u16 As[128 * 64];
  __shared__ u16 Bs[128 * 64];
  const int tid = threadIdx.x;
  const int wid = tid >> 6, lane = tid & 63;
  const int wave_m = wid >> 1, wave_n = wid & 1;
  const int m0 = blockIdx.x * 128, n0 = blockIdx.y * 128;
  const int quad = lane >> 4, col = lane & 15;

  // staging: per instr a wave covers 8 rows x 8 segs of 16B
  const int srl = lane >> 3;         // 0..7 row within 8-row staging block
  const int sseg = lane & 7;         // LDS seg slot this lane fills

  const int ra = wave_m * 64 + col;  // A row (m) this lane reads
  const int rb = wave_n * 64 + col;  // B row (n) this lane reads

  f32x4 acc[4][4];
#pragma unroll
  for (int i = 0; i < 4; ++i)
#pragma unroll
    for (int j = 0; j < 4; ++j) acc[i][j] = (f32x4){0.f, 0.f, 0.f, 0.f};

  for (int k0 = 0; k0 < 256; k0 += 64) {
#pragma unroll
    for (int blk = 0; blk < 4; ++blk) {
      const int R = wid * 32 + blk * 8;   // base row of this staging instr
      const int r = R + srl;
      const int q = (sseg - r) & 7;       // global 16B-seg fetched into slot sseg
      if (F32A) {
        const float* A = (const float*)Aptr;
        const int gm = m0 + r;
        float4 lo = make_float4(0.f, 0.f, 0.f, 0.f), hi = lo;
        if (gm < M) {
          lo = *(const float4*)(A + (size_t)gm * 256 + k0 + q * 8);
          hi = *(const float4*)(A + (size_t)gm * 256 + k0 + q * 8 + 4);
        }
        uint4 w;
        w.x = pk2bf(lo.x, lo.y); w.y = pk2bf(lo.z, lo.w);
        w.z = pk2bf(hi.x, hi.y); w.w = pk2bf(hi.z, hi.w);
        *(uint4*)&As[r * 64 + sseg * 8] = w;   // (q+r)&7 == sseg
      } else {
        const u16* A = (const u16*)Aptr;
        if (m0 + r < M)
          gl_lds16(A + (size_t)(m0 + r) * 256 + k0 + q * 8, &As[R * 64]);
      }
      gl_lds16(Wt + (size_t)(n0 + r) * 256 + k0 + q * 8, &Bs[R * 64]);
    }
    __syncthreads();

#pragma unroll
    for (int kk = 0; kk < 2; ++kk) {
      bf16x8 af[4], bf[4];
#pragma unroll
      for (int i = 0; i < 4; ++i) {
        const int r = ra + i * 16;
        af[i] = *(const bf16x8*)&As[r * 64 + ((quad + kk * 4 + r) & 7) * 8];
      }
#pragma unroll
      for (int j = 0; j < 4; ++j) {
        const int r = rb + j * 16;
        bf[j] = *(const bf16x8*)&Bs[r * 64 + ((quad + kk * 4 + r) & 7) * 8];
      }
#pragma unroll
      for (int i = 0; i < 4; ++i)
#pragma unroll
        for (int j = 0; j < 4; ++j)
          acc[i][j] = __builtin_amdgcn_mfma_f32_16x16x32_bf16(bf[j], af[i], acc[i][j], 0, 0, 0);
    }
    __syncthreads();
  }

  // epilogue (transposed fragment): m = lane&15-indexed, reg group = 4 consecutive n
#pragma unroll
  for (int i = 0; i < 4; ++i) {
    const int m = m0 + wave_m * 64 + i * 16 + col;
    if (m < M) {
      const float dd = dis[m];
#pragma unroll
      for (int j = 0; j < 4; ++j) {
        const int n = n0 + wave_n * 64 + j * 16 + quad * 4;
        uint2 o;
        o.x = pk2bf(acc[i][j][0] * dd, acc[i][j][1] * dd);
        o.y = pk2bf(acc[i][j][2] * dd, acc[i][j][3] * dd);
        *(uint2*)(C + (size_t)m * 256 + n) = o;
      }
    }
  }
}

// ---------------- Aggregate 256-dim bf16 v3 (unchanged) ----------------
__global__ __launch_bounds__(256) void k_agg256(const u16* __restrict__ u,
                                                const int* __restrict__ rs,
                                                const int* __restrict__ csr,
                                                const float* __restrict__ dis,
                                                const float* __restrict__ b,
                                                u16* __restrict__ out, int n) {
  const int wid = threadIdx.x >> 6, lane = threadIdx.x & 63;
  const int d = blockIdx.x * 4 + wid;
  if (d >= n) return;
  const int half = lane >> 5, sl = lane & 31;
  const int col = sl << 3;
  float a[8];
  {
    const int sidx = half ? n : d;
    const uint4 v = *(const uint4*)(u + (size_t)sidx * 256 + col);
    a[0] = bfl(v.x); a[1] = bfh(v.x); a[2] = bfl(v.y); a[3] = bfh(v.y);
    a[4] = bfl(v.z); a[5] = bfh(v.z); a[6] = bfl(v.w); a[7] = bfh(v.w);
  }
  const int p1 = rs[d + 1];
  for (int p = rs[d]; p < p1; p += 8) {
    int idx[4];
#pragma unroll
    for (int i = 0; i < 4; ++i) {
      const int e = p + 2 * i + half;
      idx[i] = (e < p1) ? csr[e] : n;
    }
    uint4 v[4];
#pragma unroll
    for (int i = 0; i < 4; ++i)
      v[i] = *(const uint4*)(u + (size_t)idx[i] * 256 + col);
#pragma unroll
    for (int i = 0; i < 4; ++i) {
      a[0] += bfl(v[i].x); a[1] += bfh(v[i].x);
      a[2] += bfl(v[i].y); a[3] += bfh(v[i].y);
      a[4] += bfl(v[i].z); a[5] += bfh(v[i].z);
      a[6] += bfl(v[i].w); a[7] += bfh(v[i].w);
    }
  }
#pragma unroll
  for (int j = 0; j < 8; ++j) a[j] += __shfl_xor(a[j], 32, 64);
  if (half == 0) {
    const float dd = dis[d];
    const float4 b0 = *(const float4*)(b + col);
    const float4 b1 = *(const float4*)(b + col + 4);
    uint4 o;
    o.x = pk2bf(fmaxf(dd * a[0] + b0.x, 0.f), fmaxf(dd * a[1] + b0.y, 0.f));
    o.y = pk2bf(fmaxf(dd * a[2] + b0.z, 0.f), fmaxf(dd * a[3] + b0.w, 0.f));
    o.z = pk2bf(fmaxf(dd * a[4] + b1.x, 0.f), fmaxf(dd * a[5] + b1.y, 0.f));
    o.w = pk2bf(fmaxf(dd * a[6] + b1.z, 0.f), fmaxf(dd * a[7] + b1.w, 0.f));
    *(uint4*)(out + (size_t)d * 256 + col) = o;
  }
}

// ---------------- MFMA GEMM: u40[M,40] = A_bf16[M,256] @ W2, *dis[m], fp32 out -------
// Swapped operands: lane&15 = m, reg = consecutive n -> float4 stores.
__global__ __launch_bounds__(256) void k_gemm40(const u16* __restrict__ A,
                                                const u16* __restrict__ Wt2,
                                                const float* __restrict__ dis,
                                                float* __restrict__ C, int M) {
  const int wv = threadIdx.x >> 6, lane = threadIdx.x & 63;
  const int quad = lane >> 4, col = lane & 15;
  const int m0 = blockIdx.x * 128 + wv * 32;
  f32x4 acc[2][3];
#pragma unroll
  for (int i = 0; i < 2; ++i)
#pragma unroll
    for (int j = 0; j < 3; ++j) acc[i][j] = (f32x4){0.f, 0.f, 0.f, 0.f};
  for (int k0 = 0; k0 < 256; k0 += 32) {
    bf16x8 af[2], bf[3];
#pragma unroll
    for (int i = 0; i < 2; ++i) {
      int row = m0 + i * 16 + col;
      row = (row < M) ? row : (M - 1);   // clamp; garbage rows never stored
      af[i] = *(const bf16x8*)(A + (size_t)row * 256 + k0 + quad * 8);
    }
#pragma unroll
    for (int j = 0; j < 3; ++j)
      bf[j] = *(const bf16x8*)(Wt2 + (size_t)(j * 16 + col) * 256 + k0 + quad * 8);
#pragma unroll
    for (int i = 0; i < 2; ++i)
#pragma unroll
      for (int j = 0; j < 3; ++j)
        acc[i][j] = __builtin_amdgcn_mfma_f32_16x16x32_bf16(bf[j], af[i], acc[i][j], 0, 0, 0);
  }
#pragma unroll
  for (int i = 0; i < 2; ++i) {
    const int m = m0 + i * 16 + col;
    if (m < M) {
      const float dd = dis[m];
#pragma unroll
      for (int j = 0; j < 3; ++j) {
        const int nn = j * 16 + quad * 4;
        if (nn < 40) {
          float4 o = make_float4(acc[i][j][0] * dd, acc[i][j][1] * dd,
                                 acc[i][j][2] * dd, acc[i][j][3] * dd);
          *(float4*)(C + (size_t)m * 40 + nn) = o;
        }
      }
    }
  }
}

// ---------------- Aggregate 40-dim + bias + log_softmax v2 ----------------
__global__ __launch_bounds__(256) void k_agg40(const float* __restrict__ u,
                                               const int* __restrict__ rs,
                                               const int* __restrict__ csr,
                                               const float* __restrict__ dis,
                                               const float* __restrict__ b,
                                               float* __restrict__ out, int n) {
  const int wid = threadIdx.x >> 6, lane = threadIdx.x & 63;
  const int d = blockIdx.x * 4 + wid;
  if (d >= n) return;
  const int slot = lane / 20;
  const int sl = lane % 20;
  const bool act = slot < 3;
  const int col = sl * 2;
  float a0 = 0.f, a1 = 0.f;
  if (slot == 0) {
    const float2 v = *(const float2*)(u + (size_t)d * 40 + col);
    a0 = v.x; a1 = v.y;
  }
  const int p1 = rs[d + 1];
  for (int p = rs[d]; p < p1; p += 12) {
    int idx[4];
#pragma unroll
    for (int i = 0; i < 4; ++i) {
      const int e = p + 3 * i + slot;
      idx[i] = (act && e < p1) ? csr[e] : n;
    }
    float2 v[4];
#pragma unroll
    for (int i = 0; i < 4; ++i)
      v[i] = *(const float2*)(u + (size_t)idx[i] * 40 + col);
#pragma unroll
    for (int i = 0; i < 4; ++i) { a0 += v[i].x; a1 += v[i].y; }
  }
  a0 += __shfl(a0, lane + 20, 64) + __shfl(a0, lane + 40, 64);
  a1 += __shfl(a1, lane + 20, 64) + __shfl(a1, lane + 40, 64);
  float l0 = -INFINITY, l1 = -INFINITY;
  if (lane < 20) {
    const float dd = dis[d];
    l0 = dd * a0 + b[col];
    l1 = dd * a1 + b[col + 1];
  }
  float mx = fmaxf(l0, l1);
#pragma unroll
  for (int off = 16; off; off >>= 1) mx = fmaxf(mx, __shfl_xor(mx, off, 32));
  float e0 = (lane < 20) ? expf(l0 - mx) : 0.f;
  float e1 = (lane < 20) ? expf(l1 - mx) : 0.f;
  float sm = e0 + e1;
#pragma unroll
  for (int off = 16; off; off >>= 1) sm += __shfl_xor(sm, off, 32);
  if (lane < 20) {
    const float ls = mx + logf(sm);
    float2 o = make_float2(l0 - ls, l1 - ls);
    *(float2*)(out + (size_t)d * 40 + col) = o;
  }
}

// ---------------- launch ----------------
extern "C" void kernel_launch(void* const* d_in, const int* in_sizes, int n_in,
                              void* d_out, int out_size, void* d_ws, size_t ws_size,
                              hipStream_t stream) {
  const float* x  = (const float*)d_in[0];
  const int*   ei = (const int*)d_in[1];
  const float* W0 = (const float*)d_in[2];
  const float* b0 = (const float*)d_in[3];
  const float* W1 = (const float*)d_in[4];
  const float* b1 = (const float*)d_in[5];
  const float* W2 = (const float*)d_in[6];
  const float* b2 = (const float*)d_in[7];
  float* out = (float*)d_out;

  const int N = in_sizes[0] / 256;
  const int E = in_sizes[1] / 2;
  const int* src = ei;
  const int* dst = ei + E;

  char* p = (char*)d_ws;
  auto carve = [&](size_t bytes) {
    char* q = p;
    p += (bytes + 255) & ~(size_t)255;
    return q;
  };
  u16*   bufU = (u16*)carve((size_t)(N + 1) * 256 * 2);  // +1 zero row
  u16*   bufH = (u16*)carve((size_t)(N + 1) * 256 * 2);
  float* u40  = (float*)carve((size_t)(N + 1) * 40 * 4);
  u16*   Wt0  = (u16*)carve(256 * 256 * 2);
  u16*   Wt1  = (u16*)carve(256 * 256 * 2);
  u16*   Wt2  = (u16*)carve(64 * 256 * 2);
  float* dis  = (float*)carve((size_t)N * 4);
  int*   cnt  = (int*)carve((size_t)N * 4);
  int*   rs   = (int*)carve((size_t)(N + 1) * 4);
  int*   cur  = (int*)carve((size_t)N * 4);
  int*   csr  = (int*)carve((size_t)(E + 16) * 4);
  int*   bsum = (int*)carve(1024 * 4);

  // fused prep
  const int prep_items = 65536 + 16384 + N;
  k_prep<<<(prep_items + 255) / 256, 256, 0, stream>>>(
      W0, W1, W2, Wt0, Wt1, Wt2, cnt,
      bufU + (size_t)N * 256, bufH + (size_t)N * 256, u40 + (size_t)N * 40, N);

  // CSR + deg
  const int eb = (E + 255) / 256;
  const int nb = (N + 1023) / 1024;
  k_count<<<eb, 256, 0, stream>>>(dst, cnt, E);
  k_scan1<<<nb, 1024, 0, stream>>>(cnt, rs, dis, bsum, N);
  k_scan2<<<1, 64, 0, stream>>>(bsum, rs, nb, N);
  k_scan3<<<nb, 1024, 0, stream>>>(rs, cur, bsum, N);
  k_fill<<<eb, 256, 0, stream>>>(src, dst, cur, csr, E);

  const dim3 ggrid((N + 127) / 128, 2);
  const int agrid = (N + 3) / 4;

  // layer 0 (fp32 A read directly)
  k_gemm256<true><<<ggrid, 256, 0, stream>>>(x, Wt0, dis, bufU, N);
  k_agg256<<<agrid, 256, 0, stream>>>(bufU, rs, csr, dis, b0, bufH, N);
  // layer 1
  k_gemm256<false><<<ggrid, 256, 0, stream>>>(bufH, Wt1, dis, bufU, N);
  k_agg256<<<agrid, 256, 0, stream>>>(bufU, rs, csr, dis, b1, bufH, N);
  // layer 2
  k_gemm40<<<(N + 127) / 128, 256, 0, stream>>>(bufH, Wt2, dis, u40, N);
  k_agg40<<<agrid, 256, 0, stream>>>(u40, rs, csr, dis, b2, out, N);
}